// Round 6
// baseline (424.109 us; speedup 1.0000x reference)
//
#include <hip/hip_runtime.h>
#include <cstdint>
#include <cstddef>

typedef unsigned short u16;
typedef short short8 __attribute__((ext_vector_type(8)));
typedef float floatx4 __attribute__((ext_vector_type(4)));

__device__ __forceinline__ float bf2f(u16 u) {
    union { unsigned int i; float f; } v; v.i = ((unsigned int)u) << 16; return v.f;
}
__device__ __forceinline__ u16 f2bf(float f) {
    union { float f; unsigned int i; } v; v.f = f;
    unsigned int u = v.i;
    return (u16)((u + 0x7fffu + ((u >> 16) & 1u)) >> 16);
}

#if __has_builtin(__builtin_amdgcn_exp2f)
#define EXP2F(x) __builtin_amdgcn_exp2f(x)
#else
#define EXP2F(x) exp2f(x)
#endif

// async global->LDS, 16B per lane; LDS dest = wave-uniform base + lane*16
__device__ __forceinline__ void gload_lds16(const u16* g, void* lds_wave_base) {
    __builtin_amdgcn_global_load_lds(
        (__attribute__((address_space(1))) void*)g,
        (__attribute__((address_space(3))) void*)lds_wave_base,
        16, 0, 0);
}

// ---------------------------------------------------------------------------
// Convert+transpose 4 weight matrices (E x E, f32) -> bf16. Wt[n][k]=W[k][n].
// o0..o2 are the three slices of the fused QKV Bt (consecutive), o3 = WfT.
// ---------------------------------------------------------------------------
__global__ void conv_transpose_k(const float* __restrict__ w0, const float* __restrict__ w1,
                                 const float* __restrict__ w2, const float* __restrict__ w3,
                                 u16* __restrict__ o0, u16* __restrict__ o1,
                                 u16* __restrict__ o2, u16* __restrict__ o3, int n) {
    __shared__ float t[32][33];
    const float* w; u16* o;
    switch (blockIdx.z) {
        case 0: w = w0; o = o0; break;
        case 1: w = w1; o = o1; break;
        case 2: w = w2; o = o2; break;
        default: w = w3; o = o3; break;
    }
    int tx = threadIdx.x, ty = threadIdx.y;
    int x0 = blockIdx.x * 32, y0 = blockIdx.y * 32;
    t[ty][tx] = w[(size_t)(y0 + ty) * n + x0 + tx];
    __syncthreads();
    o[(size_t)(x0 + ty) * n + y0 + tx] = f2bf(t[tx][ty]);
}

// ---------------------------------------------------------------------------
// Convert f32 -> bf16, vectorized.
// ---------------------------------------------------------------------------
__global__ void conv_k(const float* __restrict__ in, u16* __restrict__ out, int n) {
    int i = (blockIdx.x * blockDim.x + threadIdx.x) * 4;
    if (i >= n) return;
    float4 v = *(const float4*)&in[i];
    ushort4 o;
    o.x = f2bf(v.x); o.y = f2bf(v.y); o.z = f2bf(v.z); o.w = f2bf(v.w);
    *(ushort4*)&out[i] = o;
}

// ---------------------------------------------------------------------------
// Per-head V transpose from fused qkv buffer (row stride 3E, V at col 2E):
// vt[(b*16+h)*64 + d][t] = qkv[(b*T+t)*3E + 2E + h*64 + d]
// grid (T/32, 2, B*H), block (32,32)
// ---------------------------------------------------------------------------
__global__ void vtrans_k(const u16* __restrict__ qkv, u16* __restrict__ vt, int T, int E) {
    __shared__ u16 t[32][33];
    int bh = blockIdx.z;
    int b = bh >> 4, h = bh & 15;
    int t0 = blockIdx.x * 32, d0 = blockIdx.y * 32;
    int tx = threadIdx.x, ty = threadIdx.y;
    t[ty][tx] = qkv[(size_t)(b * T + t0 + ty) * (3 * E) + 2 * E + h * 64 + d0 + tx];
    __syncthreads();
    vt[((size_t)bh * 64 + d0 + ty) * T + t0 + tx] = t[tx][ty];
}

// ---------------------------------------------------------------------------
// C[M,N] = A[M,K] @ Bt[N,K]^T, bf16 in, f32 accum, bf16 out.
// 128x128 tile, BK=32, 4 waves x (4x4) 16x16x32 MFMA. global_load_lds staging.
// ---------------------------------------------------------------------------
__global__ __launch_bounds__(256) void gemm_bt(
    const u16* __restrict__ A, const u16* __restrict__ Bt, u16* __restrict__ Cb,
    int M, int N, int K) {
    __shared__ u16 lds_a[128][32];
    __shared__ u16 lds_b[128][32];

    const int tid = threadIdx.x;
    const int lane = tid & 63, wave = tid >> 6;
    const int wm = (wave >> 1) * 64, wn = (wave & 1) * 64;
    const int bm = blockIdx.x * 128, bn = blockIdx.y * 128;
    const int l15 = lane & 15, lq = lane >> 4;

    floatx4 acc[4][4];
#pragma unroll
    for (int i = 0; i < 4; ++i)
#pragma unroll
        for (int j = 0; j < 4; ++j) acc[i][j] = (floatx4)0.0f;

    for (int k0 = 0; k0 < K; k0 += 32) {
#pragma unroll
        for (int it = 0; it < 2; ++it) {
            int idx = it * 256 + tid;        // 0..511
            int row = idx >> 2;              // 0..127
            int c8 = (idx & 3) * 8;          // 0,8,16,24
            size_t ldsoff = (size_t)(it * 256 + wave * 64) * 16;  // bytes, wave-uniform
            gload_lds16(&A[(size_t)(bm + row) * K + k0 + c8], (char*)&lds_a[0][0] + ldsoff);
            gload_lds16(&Bt[(size_t)(bn + row) * K + k0 + c8], (char*)&lds_b[0][0] + ldsoff);
        }
        __syncthreads();

        short8 af[4], bfr[4];
#pragma unroll
        for (int i = 0; i < 4; ++i) af[i] = *(const short8*)&lds_a[wm + i * 16 + l15][lq * 8];
#pragma unroll
        for (int j = 0; j < 4; ++j) bfr[j] = *(const short8*)&lds_b[wn + j * 16 + l15][lq * 8];

#pragma unroll
        for (int i = 0; i < 4; ++i)
#pragma unroll
            for (int j = 0; j < 4; ++j)
                acc[i][j] = __builtin_amdgcn_mfma_f32_16x16x32_bf16(af[i], bfr[j], acc[i][j], 0, 0, 0);
        __syncthreads();
    }

#pragma unroll
    for (int i = 0; i < 4; ++i)
#pragma unroll
        for (int j = 0; j < 4; ++j)
#pragma unroll
            for (int r = 0; r < 4; ++r) {
                int row = bm + wm + i * 16 + lq * 4 + r;
                int col = bn + wn + j * 16 + l15;
                Cb[(size_t)row * N + col] = f2bf(acc[i][j][r]);
            }
}

// ---------------------------------------------------------------------------
// FF GEMM: 64x128 tile (512 blocks -> 2/CU at M=4096,N=1024). 4 waves, each
// 32x64 (2x4 MFMA tiles). Cf (f32) = bf2f(resid) + relu(acc + bias[col]).
// ---------------------------------------------------------------------------
__global__ __launch_bounds__(256) void gemm64_bt(
    const u16* __restrict__ A, const u16* __restrict__ Bt, float* __restrict__ Cf,
    const float* __restrict__ bias, const u16* __restrict__ resid,
    int M, int N, int K) {
    __shared__ u16 lds_a[64][32];
    __shared__ u16 lds_b[128][32];

    const int tid = threadIdx.x;
    const int lane = tid & 63, wave = tid >> 6;
    const int wm = (wave >> 1) * 32, wn = (wave & 1) * 64;
    const int bm = blockIdx.x * 64, bn = blockIdx.y * 128;
    const int l15 = lane & 15, lq = lane >> 4;

    floatx4 acc[2][4];
#pragma unroll
    for (int i = 0; i < 2; ++i)
#pragma unroll
        for (int j = 0; j < 4; ++j) acc[i][j] = (floatx4)0.0f;

    for (int k0 = 0; k0 < K; k0 += 32) {
        {
            int row = tid >> 2;              // 0..63
            int c8 = (tid & 3) * 8;
            size_t ldsoff = (size_t)(wave * 64) * 16;
            gload_lds16(&A[(size_t)(bm + row) * K + k0 + c8], (char*)&lds_a[0][0] + ldsoff);
        }
#pragma unroll
        for (int it = 0; it < 2; ++it) {
            int idx = it * 256 + tid;
            int row = idx >> 2;              // 0..127
            int c8 = (idx & 3) * 8;
            size_t ldsoff = (size_t)(it * 256 + wave * 64) * 16;
            gload_lds16(&Bt[(size_t)(bn + row) * K + k0 + c8], (char*)&lds_b[0][0] + ldsoff);
        }
        __syncthreads();

        short8 af[2], bfr[4];
#pragma unroll
        for (int i = 0; i < 2; ++i) af[i] = *(const short8*)&lds_a[wm + i * 16 + l15][lq * 8];
#pragma unroll
        for (int j = 0; j < 4; ++j) bfr[j] = *(const short8*)&lds_b[wn + j * 16 + l15][lq * 8];

#pragma unroll
        for (int i = 0; i < 2; ++i)
#pragma unroll
            for (int j = 0; j < 4; ++j)
                acc[i][j] = __builtin_amdgcn_mfma_f32_16x16x32_bf16(af[i], bfr[j], acc[i][j], 0, 0, 0);
        __syncthreads();
    }

#pragma unroll
    for (int i = 0; i < 2; ++i)
#pragma unroll
        for (int j = 0; j < 4; ++j)
#pragma unroll
            for (int r = 0; r < 4; ++r) {
                int row = bm + wm + i * 16 + lq * 4 + r;
                int col = bn + wn + j * 16 + l15;
                float v = acc[i][j][r];
                v = fmaxf(v + bias[col], 0.0f) + bf2f(resid[(size_t)row * N + col]);
                Cf[(size_t)row * N + col] = v;
            }
}

// ---------------------------------------------------------------------------
// Flash attention v4: software-pipelined, no-max softmax (safe: |s|/32 << 1
// for these inputs; exp2 cannot overflow), deferred PV, deferred row-sum.
// Block = 2 waves; wave 0 takes tile bx, wave 1 takes tile 127-bx (causal
// balance). K(kt+1)/V(kt) prefetched into regs; P double-buffered in LDS,
// written at iter kt, consumed at iter kt+1 (latency hidden by a full iter).
// ---------------------------------------------------------------------------
__global__ __launch_bounds__(128) void attn4_k(
    const u16* __restrict__ qkv, const u16* __restrict__ vt,
    const float* __restrict__ xf, u16* __restrict__ y, int T, int E) {
    __shared__ u16 lds_p[2][2][16][72];   // [wave][buf][row][col(64 used)]

    const int tid = threadIdx.x;
    const int lane = tid & 63, wave = tid >> 6;
    const int l15 = lane & 15, lq = lane >> 4;
    const int bh = blockIdx.y;
    const int b = bh >> 4, h = bh & 15;
    const int tile = wave ? (127 - blockIdx.x) : blockIdx.x;   // bx 0..63 -> tiles 0..127
    const int qt = tile * 16;
    const int S3 = 3 * E;

    const u16* qp = qkv + (size_t)b * T * S3 + (size_t)h * 64;
    const u16* kp = qp + E;
    const u16* vtp = vt + (size_t)bh * 64 * T;  // [64][T]

    short8 aq[2];
#pragma unroll
    for (int c = 0; c < 2; ++c)
        aq[c] = *(const short8*)&qp[(size_t)(qt + l15) * S3 + c * 32 + lq * 8];

    floatx4 o[4];
#pragma unroll
    for (int n = 0; n < 4; ++n) o[n] = (floatx4)0.0f;
    float lsum[4];
#pragma unroll
    for (int r = 0; r < 4; ++r) lsum[r] = 0.0f;

    const float c2 = 0.04508422f;  // log2(e)/32
    const int nkb = (qt >> 6) + 1; // 64-wide chunks covering cols 0..qt+15

    short8 kf[2][8];   // [buf][t2*2+c] K fragments, double-buffered
    short8 vf[8], vf2[8];

    // prologue: K(0)
#pragma unroll
    for (int t2 = 0; t2 < 4; ++t2)
#pragma unroll
        for (int c = 0; c < 2; ++c)
            kf[0][t2 * 2 + c] = *(const short8*)&kp[(size_t)(t2 * 16 + l15) * S3 + c * 32 + lq * 8];

    for (int kt = 0; kt < nkb; ++kt) {
        const int kc0 = kt << 6;

        // prefetch K(kt+1)
        if (kt + 1 < nkb) {
            const int nc0 = kc0 + 64;
#pragma unroll
            for (int t2 = 0; t2 < 4; ++t2)
#pragma unroll
                for (int c = 0; c < 2; ++c)
                    kf[(kt + 1) & 1][t2 * 2 + c] =
                        *(const short8*)&kp[(size_t)(nc0 + t2 * 16 + l15) * S3 + c * 32 + lq * 8];
        }
        // V(kt) loads (consumed next iteration / epilogue)
#pragma unroll
        for (int kc = 0; kc < 2; ++kc)
#pragma unroll
            for (int n = 0; n < 4; ++n)
                vf2[kc * 4 + n] = *(const short8*)&vtp[(size_t)(n * 16 + l15) * T + kc0 + kc * 32 + lq * 8];

        // S = Q K^T with current (prefetched) K
        floatx4 s[4];
#pragma unroll
        for (int t2 = 0; t2 < 4; ++t2) {
            floatx4 sa = (floatx4)0.0f;
            sa = __builtin_amdgcn_mfma_f32_16x16x32_bf16(aq[0], kf[kt & 1][t2 * 2 + 0], sa, 0, 0, 0);
            sa = __builtin_amdgcn_mfma_f32_16x16x32_bf16(aq[1], kf[kt & 1][t2 * 2 + 1], sa, 0, 0, 0);
            s[t2] = sa;
        }

        // deferred PV of chunk kt-1 (P written last iter, LDS latency hidden)
        if (kt > 0) {
#pragma unroll
            for (int kc = 0; kc < 2; ++kc) {
                short8 ap = *(const short8*)&lds_p[wave][(kt - 1) & 1][l15][kc * 32 + lq * 8];
#pragma unroll
                for (int n = 0; n < 4; ++n)
                    o[n] = __builtin_amdgcn_mfma_f32_16x16x32_bf16(ap, vf[kc * 4 + n], o[n], 0, 0, 0);
            }
        }

        // softmax numerator (no max subtraction needed for this score scale)
        const bool partial = (kc0 + 63 > qt);  // wave-uniform: only diagonal chunk
#pragma unroll
        for (int t2 = 0; t2 < 4; ++t2)
#pragma unroll
            for (int r = 0; r < 4; ++r) {
                float p;
                if (partial) {
                    int colg = kc0 + t2 * 16 + l15;
                    int rowg = qt + lq * 4 + r;
                    p = (colg <= rowg) ? EXP2F(s[t2][r] * c2) : 0.0f;
                } else {
                    p = EXP2F(s[t2][r] * c2);
                }
                lsum[r] += p;
                lds_p[wave][kt & 1][lq * 4 + r][t2 * 16 + l15] = f2bf(p);
            }

        // rotate V buffer
#pragma unroll
        for (int i = 0; i < 8; ++i) vf[i] = vf2[i];
    }

    // epilogue PV for the last chunk
#pragma unroll
    for (int kc = 0; kc < 2; ++kc) {
        short8 ap = *(const short8*)&lds_p[wave][(nkb - 1) & 1][l15][kc * 32 + lq * 8];
#pragma unroll
        for (int n = 0; n < 4; ++n)
            o[n] = __builtin_amdgcn_mfma_f32_16x16x32_bf16(ap, vf[kc * 4 + n], o[n], 0, 0, 0);
    }

    // one final row-sum reduction across the 16-lane groups
#pragma unroll
    for (int r = 0; r < 4; ++r) {
#pragma unroll
        for (int msk = 1; msk < 16; msk <<= 1) lsum[r] += __shfl_xor(lsum[r], msk, 64);
    }

    // epilogue: y = x + O/l (bf16 out, f32 residual in)
    const float* xp = xf + (size_t)b * T * E + (size_t)h * 64;
    u16* yp = y + (size_t)b * T * E + (size_t)h * 64;
    float rl[4];
#pragma unroll
    for (int r = 0; r < 4; ++r) rl[r] = 1.0f / lsum[r];
#pragma unroll
    for (int n = 0; n < 4; ++n)
#pragma unroll
        for (int r = 0; r < 4; ++r) {
            int rowg = qt + lq * 4 + r;
            int col = n * 16 + l15;
            float val = o[n][r] * rl[r];
            float res = xp[(size_t)rowg * E + col];
            yp[(size_t)rowg * E + col] = f2bf(res + val);
        }
}

// ---------------------------------------------------------------------------
extern "C" void kernel_launch(void* const* d_in, const int* in_sizes, int n_in,
                              void* d_out, int out_size, void* d_ws, size_t ws_size,
                              hipStream_t stream) {
    const int B = 2, T = 2048, E = 1024;
    const int M = B * T;  // 4096

    const float* x  = (const float*)d_in[0];
    const float* Wq = (const float*)d_in[1];
    const float* Wk = (const float*)d_in[2];
    const float* Wv = (const float*)d_in[3];
    const float* Wf = (const float*)d_in[4];
    const float* bf = (const float*)d_in[5];
    float* out = (float*)d_out;

    u16* ws = (u16*)d_ws;
    const size_t WN = (size_t)E * E;      // 1M elems per weight
    const size_t XN = (size_t)M * E;      // 4M elems per activation
    u16* Wqkv = ws;                        // [3E][E] fused transposed weights
    u16* WfT  = ws + 3 * WN;
    u16* xb   = ws + 4 * WN;               // aliased by vt after QKV GEMM
    u16* qkv  = ws + 4 * WN + XN;          // [M][3E] = 3*XN elems
    u16* yb   = ws + 4 * WN + 4 * XN;
    u16* vt   = xb;                        // BH*64*T = XN elems

    conv_transpose_k<<<dim3(E / 32, E / 32, 4), dim3(32, 32), 0, stream>>>(
        Wq, Wk, Wv, Wf, Wqkv, Wqkv + WN, Wqkv + 2 * WN, WfT, E);
    conv_k<<<(int)(XN / 1024), 256, 0, stream>>>(x, xb, (int)XN);

    // fused QKV projection: [M,E] @ [E,3E] -> [M,3E]
    gemm_bt<<<dim3(M / 128, 3 * E / 128), 256, 0, stream>>>(xb, Wqkv, qkv, M, 3 * E, E);

    vtrans_k<<<dim3(T / 32, 2, B * 16), dim3(32, 32), 0, stream>>>(qkv, vt, T, E);

    // 128 q-tiles, 2 waves/block -> 64 blocks in x
    attn4_k<<<dim3(T / 16 / 2, B * 16), 128, 0, stream>>>(qkv, vt, x, yb, T, E);

    // FF: out = yb + relu(yb @ Wf + bf)
    gemm64_bt<<<dim3(M / 64, E / 128), 256, 0, stream>>>(yb, WfT, out, bf, yb, M, E, E);
}

// Round 7
// 294.577 us; speedup vs baseline: 1.4397x; 1.4397x over previous
//
#include <hip/hip_runtime.h>
#include <cstdint>
#include <cstddef>

typedef unsigned short u16;
typedef short short8 __attribute__((ext_vector_type(8)));
typedef float floatx4 __attribute__((ext_vector_type(4)));

__device__ __forceinline__ float bf2f(u16 u) {
    union { unsigned int i; float f; } v; v.i = ((unsigned int)u) << 16; return v.f;
}
__device__ __forceinline__ u16 f2bf(float f) {
    union { float f; unsigned int i; } v; v.f = f;
    unsigned int u = v.i;
    return (u16)((u + 0x7fffu + ((u >> 16) & 1u)) >> 16);
}

#if __has_builtin(__builtin_amdgcn_exp2f)
#define EXP2F(x) __builtin_amdgcn_exp2f(x)
#else
#define EXP2F(x) exp2f(x)
#endif

// async global->LDS, 16B per lane; LDS dest = wave-uniform base + lane*16
__device__ __forceinline__ void gload_lds16(const u16* g, void* lds_wave_base) {
    __builtin_amdgcn_global_load_lds(
        (__attribute__((address_space(1))) void*)g,
        (__attribute__((address_space(3))) void*)lds_wave_base,
        16, 0, 0);
}

// ---------------------------------------------------------------------------
// Convert+transpose 4 weight matrices (E x E, f32) -> bf16. Wt[n][k]=W[k][n].
// o0..o2 are the three slices of the fused QKV Bt (consecutive), o3 = WfT.
// ---------------------------------------------------------------------------
__global__ void conv_transpose_k(const float* __restrict__ w0, const float* __restrict__ w1,
                                 const float* __restrict__ w2, const float* __restrict__ w3,
                                 u16* __restrict__ o0, u16* __restrict__ o1,
                                 u16* __restrict__ o2, u16* __restrict__ o3, int n) {
    __shared__ float t[32][33];
    const float* w; u16* o;
    switch (blockIdx.z) {
        case 0: w = w0; o = o0; break;
        case 1: w = w1; o = o1; break;
        case 2: w = w2; o = o2; break;
        default: w = w3; o = o3; break;
    }
    int tx = threadIdx.x, ty = threadIdx.y;
    int x0 = blockIdx.x * 32, y0 = blockIdx.y * 32;
    t[ty][tx] = w[(size_t)(y0 + ty) * n + x0 + tx];
    __syncthreads();
    o[(size_t)(x0 + ty) * n + y0 + tx] = f2bf(t[tx][ty]);
}

// ---------------------------------------------------------------------------
// Convert f32 -> bf16, vectorized.
// ---------------------------------------------------------------------------
__global__ void conv_k(const float* __restrict__ in, u16* __restrict__ out, int n) {
    int i = (blockIdx.x * blockDim.x + threadIdx.x) * 4;
    if (i >= n) return;
    float4 v = *(const float4*)&in[i];
    ushort4 o;
    o.x = f2bf(v.x); o.y = f2bf(v.y); o.z = f2bf(v.z); o.w = f2bf(v.w);
    *(ushort4*)&out[i] = o;
}

// ---------------------------------------------------------------------------
// Per-head V transpose from fused qkv buffer (row stride 3E, V at col 2E):
// vt[(b*16+h)*64 + d][t] = qkv[(b*T+t)*3E + 2E + h*64 + d]
// ---------------------------------------------------------------------------
__global__ void vtrans_k(const u16* __restrict__ qkv, u16* __restrict__ vt, int T, int E) {
    __shared__ u16 t[32][33];
    int bh = blockIdx.z;
    int b = bh >> 4, h = bh & 15;
    int t0 = blockIdx.x * 32, d0 = blockIdx.y * 32;
    int tx = threadIdx.x, ty = threadIdx.y;
    t[ty][tx] = qkv[(size_t)(b * T + t0 + ty) * (3 * E) + 2 * E + h * 64 + d0 + tx];
    __syncthreads();
    vt[((size_t)bh * 64 + d0 + ty) * T + t0 + tx] = t[tx][ty];
}

// ---------------------------------------------------------------------------
// C[M,N] = A[M,K] @ Bt[N,K]^T, bf16 in, f32 accum, bf16 out.
// 128x128 tile, BK=32, 4 waves x (4x4) 16x16x32 MFMA. global_load_lds staging.
// ---------------------------------------------------------------------------
__global__ __launch_bounds__(256) void gemm_bt(
    const u16* __restrict__ A, const u16* __restrict__ Bt, u16* __restrict__ Cb,
    int M, int N, int K) {
    __shared__ u16 lds_a[128][32];
    __shared__ u16 lds_b[128][32];

    const int tid = threadIdx.x;
    const int lane = tid & 63, wave = tid >> 6;
    const int wm = (wave >> 1) * 64, wn = (wave & 1) * 64;
    const int bm = blockIdx.x * 128, bn = blockIdx.y * 128;
    const int l15 = lane & 15, lq = lane >> 4;

    floatx4 acc[4][4];
#pragma unroll
    for (int i = 0; i < 4; ++i)
#pragma unroll
        for (int j = 0; j < 4; ++j) acc[i][j] = (floatx4)0.0f;

    for (int k0 = 0; k0 < K; k0 += 32) {
#pragma unroll
        for (int it = 0; it < 2; ++it) {
            int idx = it * 256 + tid;        // 0..511
            int row = idx >> 2;              // 0..127
            int c8 = (idx & 3) * 8;          // 0,8,16,24
            size_t ldsoff = (size_t)(it * 256 + wave * 64) * 16;  // bytes, wave-uniform
            gload_lds16(&A[(size_t)(bm + row) * K + k0 + c8], (char*)&lds_a[0][0] + ldsoff);
            gload_lds16(&Bt[(size_t)(bn + row) * K + k0 + c8], (char*)&lds_b[0][0] + ldsoff);
        }
        __syncthreads();

        short8 af[4], bfr[4];
#pragma unroll
        for (int i = 0; i < 4; ++i) af[i] = *(const short8*)&lds_a[wm + i * 16 + l15][lq * 8];
#pragma unroll
        for (int j = 0; j < 4; ++j) bfr[j] = *(const short8*)&lds_b[wn + j * 16 + l15][lq * 8];

#pragma unroll
        for (int i = 0; i < 4; ++i)
#pragma unroll
            for (int j = 0; j < 4; ++j)
                acc[i][j] = __builtin_amdgcn_mfma_f32_16x16x32_bf16(af[i], bfr[j], acc[i][j], 0, 0, 0);
        __syncthreads();
    }

#pragma unroll
    for (int i = 0; i < 4; ++i)
#pragma unroll
        for (int j = 0; j < 4; ++j)
#pragma unroll
            for (int r = 0; r < 4; ++r) {
                int row = bm + wm + i * 16 + lq * 4 + r;
                int col = bn + wn + j * 16 + l15;
                Cb[(size_t)row * N + col] = f2bf(acc[i][j][r]);
            }
}

// ---------------------------------------------------------------------------
// FF GEMM: 64x128 tile. Cf (f32) = bf2f(resid) + relu(acc + bias[col]).
// ---------------------------------------------------------------------------
__global__ __launch_bounds__(256) void gemm64_bt(
    const u16* __restrict__ A, const u16* __restrict__ Bt, float* __restrict__ Cf,
    const float* __restrict__ bias, const u16* __restrict__ resid,
    int M, int N, int K) {
    __shared__ u16 lds_a[64][32];
    __shared__ u16 lds_b[128][32];

    const int tid = threadIdx.x;
    const int lane = tid & 63, wave = tid >> 6;
    const int wm = (wave >> 1) * 32, wn = (wave & 1) * 64;
    const int bm = blockIdx.x * 64, bn = blockIdx.y * 128;
    const int l15 = lane & 15, lq = lane >> 4;

    floatx4 acc[2][4];
#pragma unroll
    for (int i = 0; i < 2; ++i)
#pragma unroll
        for (int j = 0; j < 4; ++j) acc[i][j] = (floatx4)0.0f;

    for (int k0 = 0; k0 < K; k0 += 32) {
        {
            int row = tid >> 2;              // 0..63
            int c8 = (tid & 3) * 8;
            size_t ldsoff = (size_t)(wave * 64) * 16;
            gload_lds16(&A[(size_t)(bm + row) * K + k0 + c8], (char*)&lds_a[0][0] + ldsoff);
        }
#pragma unroll
        for (int it = 0; it < 2; ++it) {
            int idx = it * 256 + tid;
            int row = idx >> 2;              // 0..127
            int c8 = (idx & 3) * 8;
            size_t ldsoff = (size_t)(it * 256 + wave * 64) * 16;
            gload_lds16(&Bt[(size_t)(bn + row) * K + k0 + c8], (char*)&lds_b[0][0] + ldsoff);
        }
        __syncthreads();

        short8 af[2], bfr[4];
#pragma unroll
        for (int i = 0; i < 2; ++i) af[i] = *(const short8*)&lds_a[wm + i * 16 + l15][lq * 8];
#pragma unroll
        for (int j = 0; j < 4; ++j) bfr[j] = *(const short8*)&lds_b[wn + j * 16 + l15][lq * 8];

#pragma unroll
        for (int i = 0; i < 2; ++i)
#pragma unroll
            for (int j = 0; j < 4; ++j)
                acc[i][j] = __builtin_amdgcn_mfma_f32_16x16x32_bf16(af[i], bfr[j], acc[i][j], 0, 0, 0);
        __syncthreads();
    }

#pragma unroll
    for (int i = 0; i < 2; ++i)
#pragma unroll
        for (int j = 0; j < 4; ++j)
#pragma unroll
            for (int r = 0; r < 4; ++r) {
                int row = bm + wm + i * 16 + lq * 4 + r;
                int col = bn + wn + j * 16 + l15;
                float v = acc[i][j][r];
                v = fmaxf(v + bias[col], 0.0f) + bf2f(resid[(size_t)row * N + col]);
                Cf[(size_t)row * N + col] = v;
            }
}

// ---------------------------------------------------------------------------
// Flash attention v5: pipelined with COMPILE-TIME K buffer alternation
// (fixes v4's dynamic-index scratch spills). Per iteration kt:
//   issue K(kt+1)->KFN, V(kt-1)->vf; S=Q K(kt)^T (KFC); softmax+write P(kt);
//   PV(kt-1) last (V load has a full iteration of slack, P a full iter).
// No-max softmax (validated round 6); single row-sum reduction at the end.
// ---------------------------------------------------------------------------
#define ATTN_STEP(KT, KFC, KFN)                                                   \
    {                                                                             \
        const int kc0_ = (KT) << 6;                                               \
        if ((KT) + 1 < nkb) {                                                     \
            const int nc0_ = kc0_ + 64;                                           \
            _Pragma("unroll")                                                     \
            for (int t2 = 0; t2 < 4; ++t2)                                        \
                _Pragma("unroll")                                                 \
                for (int c = 0; c < 2; ++c)                                       \
                    KFN[t2 * 2 + c] = *(const short8*)&kp[                        \
                        (size_t)(nc0_ + t2 * 16 + l15) * S3 + c * 32 + lq * 8];   \
        }                                                                         \
        if ((KT) > 0) {                                                           \
            const int pc0_ = kc0_ - 64;                                           \
            _Pragma("unroll")                                                     \
            for (int kc = 0; kc < 2; ++kc)                                        \
                _Pragma("unroll")                                                 \
                for (int n = 0; n < 4; ++n)                                       \
                    vf[kc * 4 + n] = *(const short8*)&vtp[                        \
                        (size_t)(n * 16 + l15) * T + pc0_ + kc * 32 + lq * 8];    \
        }                                                                         \
        floatx4 s_[4];                                                            \
        _Pragma("unroll")                                                         \
        for (int t2 = 0; t2 < 4; ++t2) {                                          \
            floatx4 sa_ = (floatx4)0.0f;                                          \
            sa_ = __builtin_amdgcn_mfma_f32_16x16x32_bf16(aq[0], KFC[t2 * 2 + 0], sa_, 0, 0, 0); \
            sa_ = __builtin_amdgcn_mfma_f32_16x16x32_bf16(aq[1], KFC[t2 * 2 + 1], sa_, 0, 0, 0); \
            s_[t2] = sa_;                                                         \
        }                                                                         \
        const bool partial_ = (kc0_ + 63 > qt);                                   \
        _Pragma("unroll")                                                         \
        for (int t2 = 0; t2 < 4; ++t2)                                            \
            _Pragma("unroll")                                                     \
            for (int r = 0; r < 4; ++r) {                                         \
                float p_;                                                         \
                if (partial_) {                                                   \
                    int colg_ = kc0_ + t2 * 16 + l15;                             \
                    int rowg_ = qt + lq * 4 + r;                                  \
                    p_ = (colg_ <= rowg_) ? EXP2F(s_[t2][r] * c2) : 0.0f;         \
                } else {                                                          \
                    p_ = EXP2F(s_[t2][r] * c2);                                   \
                }                                                                 \
                lsum[r] += p_;                                                    \
                lds_p[wave][(KT) & 1][lq * 4 + r][t2 * 16 + l15] = f2bf(p_);      \
            }                                                                     \
        if ((KT) > 0) {                                                           \
            _Pragma("unroll")                                                     \
            for (int kc = 0; kc < 2; ++kc) {                                      \
                short8 ap_ = *(const short8*)&lds_p[wave][((KT) - 1) & 1][l15][kc * 32 + lq * 8]; \
                _Pragma("unroll")                                                 \
                for (int n = 0; n < 4; ++n)                                       \
                    o[n] = __builtin_amdgcn_mfma_f32_16x16x32_bf16(ap_, vf[kc * 4 + n], o[n], 0, 0, 0); \
            }                                                                     \
        }                                                                         \
    }

__global__ __launch_bounds__(128) void attn5_k(
    const u16* __restrict__ qkv, const u16* __restrict__ vt,
    const float* __restrict__ xf, u16* __restrict__ y, int T, int E) {
    __shared__ u16 lds_p[2][2][16][72];   // [wave][buf][row][col(64 used)]

    const int tid = threadIdx.x;
    const int lane = tid & 63, wave = tid >> 6;
    const int l15 = lane & 15, lq = lane >> 4;
    const int bh = blockIdx.y;
    const int b = bh >> 4, h = bh & 15;
    const int tile = wave ? (127 - blockIdx.x) : blockIdx.x;   // bx 0..63 -> tiles 0..127
    const int qt = tile * 16;
    const int S3 = 3 * E;

    const u16* qp = qkv + (size_t)b * T * S3 + (size_t)h * 64;
    const u16* kp = qp + E;
    const u16* vtp = vt + (size_t)bh * 64 * T;  // [64][T]

    short8 aq[2];
#pragma unroll
    for (int c = 0; c < 2; ++c)
        aq[c] = *(const short8*)&qp[(size_t)(qt + l15) * S3 + c * 32 + lq * 8];

    floatx4 o[4];
#pragma unroll
    for (int n = 0; n < 4; ++n) o[n] = (floatx4)0.0f;
    float lsum[4];
#pragma unroll
    for (int r = 0; r < 4; ++r) lsum[r] = 0.0f;

    const float c2 = 0.04508422f;  // log2(e)/32
    const int nkb = (qt >> 6) + 1; // 64-wide chunks covering cols 0..qt+15

    short8 kfA[8], kfB[8], vf[8];

    // prologue: K(0) -> kfA
#pragma unroll
    for (int t2 = 0; t2 < 4; ++t2)
#pragma unroll
        for (int c = 0; c < 2; ++c)
            kfA[t2 * 2 + c] = *(const short8*)&kp[(size_t)(t2 * 16 + l15) * S3 + c * 32 + lq * 8];

    int kt = 0;
    while (true) {
        ATTN_STEP(kt, kfA, kfB);
        ++kt;
        if (kt == nkb) break;
        ATTN_STEP(kt, kfB, kfA);
        ++kt;
        if (kt == nkb) break;
    }

    // final PV for chunk nkb-1
    {
        const int pc0 = (nkb - 1) << 6;
#pragma unroll
        for (int kc = 0; kc < 2; ++kc)
#pragma unroll
            for (int n = 0; n < 4; ++n)
                vf[kc * 4 + n] = *(const short8*)&vtp[(size_t)(n * 16 + l15) * T + pc0 + kc * 32 + lq * 8];
#pragma unroll
        for (int kc = 0; kc < 2; ++kc) {
            short8 ap = *(const short8*)&lds_p[wave][(nkb - 1) & 1][l15][kc * 32 + lq * 8];
#pragma unroll
            for (int n = 0; n < 4; ++n)
                o[n] = __builtin_amdgcn_mfma_f32_16x16x32_bf16(ap, vf[kc * 4 + n], o[n], 0, 0, 0);
        }
    }

    // one final row-sum reduction across the 16-lane groups
#pragma unroll
    for (int r = 0; r < 4; ++r) {
#pragma unroll
        for (int msk = 1; msk < 16; msk <<= 1) lsum[r] += __shfl_xor(lsum[r], msk, 64);
    }

    // epilogue: y = x + O/l (bf16 out, f32 residual in)
    const float* xp = xf + (size_t)b * T * E + (size_t)h * 64;
    u16* yp = y + (size_t)b * T * E + (size_t)h * 64;
    float rl[4];
#pragma unroll
    for (int r = 0; r < 4; ++r) rl[r] = 1.0f / lsum[r];
#pragma unroll
    for (int n = 0; n < 4; ++n)
#pragma unroll
        for (int r = 0; r < 4; ++r) {
            int rowg = qt + lq * 4 + r;
            int col = n * 16 + l15;
            float val = o[n][r] * rl[r];
            float res = xp[(size_t)rowg * E + col];
            yp[(size_t)rowg * E + col] = f2bf(res + val);
        }
}

// ---------------------------------------------------------------------------
extern "C" void kernel_launch(void* const* d_in, const int* in_sizes, int n_in,
                              void* d_out, int out_size, void* d_ws, size_t ws_size,
                              hipStream_t stream) {
    const int B = 2, T = 2048, E = 1024;
    const int M = B * T;  // 4096

    const float* x  = (const float*)d_in[0];
    const float* Wq = (const float*)d_in[1];
    const float* Wk = (const float*)d_in[2];
    const float* Wv = (const float*)d_in[3];
    const float* Wf = (const float*)d_in[4];
    const float* bf = (const float*)d_in[5];
    float* out = (float*)d_out;

    u16* ws = (u16*)d_ws;
    const size_t WN = (size_t)E * E;      // 1M elems per weight
    const size_t XN = (size_t)M * E;      // 4M elems per activation
    u16* Wqkv = ws;                        // [3E][E] fused transposed weights
    u16* WfT  = ws + 3 * WN;
    u16* xb   = ws + 4 * WN;               // aliased by vt after QKV GEMM
    u16* qkv  = ws + 4 * WN + XN;          // [M][3E] = 3*XN elems
    u16* yb   = ws + 4 * WN + 4 * XN;
    u16* vt   = xb;                        // BH*64*T = XN elems

    conv_transpose_k<<<dim3(E / 32, E / 32, 4), dim3(32, 32), 0, stream>>>(
        Wq, Wk, Wv, Wf, Wqkv, Wqkv + WN, Wqkv + 2 * WN, WfT, E);
    conv_k<<<(int)(XN / 1024), 256, 0, stream>>>(x, xb, (int)XN);

    // fused QKV projection: [M,E] @ [E,3E] -> [M,3E]
    gemm_bt<<<dim3(M / 128, 3 * E / 128), 256, 0, stream>>>(xb, Wqkv, qkv, M, 3 * E, E);

    vtrans_k<<<dim3(T / 32, 2, B * 16), dim3(32, 32), 0, stream>>>(qkv, vt, T, E);

    // 128 q-tiles, 2 waves/block -> 64 blocks in x
    attn5_k<<<dim3(T / 16 / 2, B * 16), 128, 0, stream>>>(qkv, vt, x, yb, T, E);

    // FF: out = yb + relu(yb @ Wf + bf)
    gemm64_bt<<<dim3(M / 64, E / 128), 256, 0, stream>>>(yb, WfT, out, bf, yb, M, E, E);
}

// Round 8
// 289.112 us; speedup vs baseline: 1.4669x; 1.0189x over previous
//
#include <hip/hip_runtime.h>
#include <cstdint>
#include <cstddef>

typedef unsigned short u16;
typedef short short8 __attribute__((ext_vector_type(8)));
typedef float floatx4 __attribute__((ext_vector_type(4)));

__device__ __forceinline__ float bf2f(u16 u) {
    union { unsigned int i; float f; } v; v.i = ((unsigned int)u) << 16; return v.f;
}
__device__ __forceinline__ u16 f2bf(float f) {
    union { float f; unsigned int i; } v; v.f = f;
    unsigned int u = v.i;
    return (u16)((u + 0x7fffu + ((u >> 16) & 1u)) >> 16);
}

#if __has_builtin(__builtin_amdgcn_exp2f)
#define EXP2F(x) __builtin_amdgcn_exp2f(x)
#else
#define EXP2F(x) exp2f(x)
#endif

// async global->LDS, 16B per lane; LDS dest = wave-uniform base + lane*16
__device__ __forceinline__ void gload_lds16(const u16* g, void* lds_wave_base) {
    __builtin_amdgcn_global_load_lds(
        (__attribute__((address_space(1))) void*)g,
        (__attribute__((address_space(3))) void*)lds_wave_base,
        16, 0, 0);
}

// ---------------------------------------------------------------------------
// Convert+transpose 4 weight matrices (E x E, f32) -> bf16. Wt[n][k]=W[k][n].
// ---------------------------------------------------------------------------
__global__ void conv_transpose_k(const float* __restrict__ w0, const float* __restrict__ w1,
                                 const float* __restrict__ w2, const float* __restrict__ w3,
                                 u16* __restrict__ o0, u16* __restrict__ o1,
                                 u16* __restrict__ o2, u16* __restrict__ o3, int n) {
    __shared__ float t[32][33];
    const float* w; u16* o;
    switch (blockIdx.z) {
        case 0: w = w0; o = o0; break;
        case 1: w = w1; o = o1; break;
        case 2: w = w2; o = o2; break;
        default: w = w3; o = o3; break;
    }
    int tx = threadIdx.x, ty = threadIdx.y;
    int x0 = blockIdx.x * 32, y0 = blockIdx.y * 32;
    t[ty][tx] = w[(size_t)(y0 + ty) * n + x0 + tx];
    __syncthreads();
    o[(size_t)(x0 + ty) * n + y0 + tx] = f2bf(t[tx][ty]);
}

// ---------------------------------------------------------------------------
// Convert f32 -> bf16, vectorized.
// ---------------------------------------------------------------------------
__global__ void conv_k(const float* __restrict__ in, u16* __restrict__ out, int n) {
    int i = (blockIdx.x * blockDim.x + threadIdx.x) * 4;
    if (i >= n) return;
    float4 v = *(const float4*)&in[i];
    ushort4 o;
    o.x = f2bf(v.x); o.y = f2bf(v.y); o.z = f2bf(v.z); o.w = f2bf(v.w);
    *(ushort4*)&out[i] = o;
}

// ---------------------------------------------------------------------------
// Per-head V transpose from fused qkv buffer (row stride 3E, V at col 2E):
// vt[(b*16+h)*64 + d][t] = qkv[(b*T+t)*3E + 2E + h*64 + d]
// ---------------------------------------------------------------------------
__global__ void vtrans_k(const u16* __restrict__ qkv, u16* __restrict__ vt, int T, int E) {
    __shared__ u16 t[32][33];
    int bh = blockIdx.z;
    int b = bh >> 4, h = bh & 15;
    int t0 = blockIdx.x * 32, d0 = blockIdx.y * 32;
    int tx = threadIdx.x, ty = threadIdx.y;
    t[ty][tx] = qkv[(size_t)(b * T + t0 + ty) * (3 * E) + 2 * E + h * 64 + d0 + tx];
    __syncthreads();
    vt[((size_t)bh * 64 + d0 + ty) * T + t0 + tx] = t[tx][ty];
}

// ---------------------------------------------------------------------------
// C[M,N] = A[M,K] @ Bt[N,K]^T, bf16 in, f32 accum, bf16 out.
// 128x128 tile, BK=32, 4 waves x (4x4) 16x16x32 MFMA. global_load_lds staging.
// ---------------------------------------------------------------------------
__global__ __launch_bounds__(256) void gemm_bt(
    const u16* __restrict__ A, const u16* __restrict__ Bt, u16* __restrict__ Cb,
    int M, int N, int K) {
    __shared__ u16 lds_a[128][32];
    __shared__ u16 lds_b[128][32];

    const int tid = threadIdx.x;
    const int lane = tid & 63, wave = tid >> 6;
    const int wm = (wave >> 1) * 64, wn = (wave & 1) * 64;
    const int bm = blockIdx.x * 128, bn = blockIdx.y * 128;
    const int l15 = lane & 15, lq = lane >> 4;

    floatx4 acc[4][4];
#pragma unroll
    for (int i = 0; i < 4; ++i)
#pragma unroll
        for (int j = 0; j < 4; ++j) acc[i][j] = (floatx4)0.0f;

    for (int k0 = 0; k0 < K; k0 += 32) {
#pragma unroll
        for (int it = 0; it < 2; ++it) {
            int idx = it * 256 + tid;        // 0..511
            int row = idx >> 2;              // 0..127
            int c8 = (idx & 3) * 8;          // 0,8,16,24
            size_t ldsoff = (size_t)(it * 256 + wave * 64) * 16;  // bytes, wave-uniform
            gload_lds16(&A[(size_t)(bm + row) * K + k0 + c8], (char*)&lds_a[0][0] + ldsoff);
            gload_lds16(&Bt[(size_t)(bn + row) * K + k0 + c8], (char*)&lds_b[0][0] + ldsoff);
        }
        __syncthreads();

        short8 af[4], bfr[4];
#pragma unroll
        for (int i = 0; i < 4; ++i) af[i] = *(const short8*)&lds_a[wm + i * 16 + l15][lq * 8];
#pragma unroll
        for (int j = 0; j < 4; ++j) bfr[j] = *(const short8*)&lds_b[wn + j * 16 + l15][lq * 8];

#pragma unroll
        for (int i = 0; i < 4; ++i)
#pragma unroll
            for (int j = 0; j < 4; ++j)
                acc[i][j] = __builtin_amdgcn_mfma_f32_16x16x32_bf16(af[i], bfr[j], acc[i][j], 0, 0, 0);
        __syncthreads();
    }

#pragma unroll
    for (int i = 0; i < 4; ++i)
#pragma unroll
        for (int j = 0; j < 4; ++j)
#pragma unroll
            for (int r = 0; r < 4; ++r) {
                int row = bm + wm + i * 16 + lq * 4 + r;
                int col = bn + wn + j * 16 + l15;
                Cb[(size_t)row * N + col] = f2bf(acc[i][j][r]);
            }
}

// ---------------------------------------------------------------------------
// FF GEMM: 64x128 tile. Cf (f32) = bf2f(resid) + relu(acc + bias[col]).
// ---------------------------------------------------------------------------
__global__ __launch_bounds__(256) void gemm64_bt(
    const u16* __restrict__ A, const u16* __restrict__ Bt, float* __restrict__ Cf,
    const float* __restrict__ bias, const u16* __restrict__ resid,
    int M, int N, int K) {
    __shared__ u16 lds_a[64][32];
    __shared__ u16 lds_b[128][32];

    const int tid = threadIdx.x;
    const int lane = tid & 63, wave = tid >> 6;
    const int wm = (wave >> 1) * 32, wn = (wave & 1) * 64;
    const int bm = blockIdx.x * 64, bn = blockIdx.y * 128;
    const int l15 = lane & 15, lq = lane >> 4;

    floatx4 acc[2][4];
#pragma unroll
    for (int i = 0; i < 2; ++i)
#pragma unroll
        for (int j = 0; j < 4; ++j) acc[i][j] = (floatx4)0.0f;

    for (int k0 = 0; k0 < K; k0 += 32) {
        {
            int row = tid >> 2;              // 0..63
            int c8 = (tid & 3) * 8;
            size_t ldsoff = (size_t)(wave * 64) * 16;
            gload_lds16(&A[(size_t)(bm + row) * K + k0 + c8], (char*)&lds_a[0][0] + ldsoff);
        }
#pragma unroll
        for (int it = 0; it < 2; ++it) {
            int idx = it * 256 + tid;
            int row = idx >> 2;              // 0..127
            int c8 = (idx & 3) * 8;
            size_t ldsoff = (size_t)(it * 256 + wave * 64) * 16;
            gload_lds16(&Bt[(size_t)(bn + row) * K + k0 + c8], (char*)&lds_b[0][0] + ldsoff);
        }
        __syncthreads();

        short8 af[2], bfr[4];
#pragma unroll
        for (int i = 0; i < 2; ++i) af[i] = *(const short8*)&lds_a[wm + i * 16 + l15][lq * 8];
#pragma unroll
        for (int j = 0; j < 4; ++j) bfr[j] = *(const short8*)&lds_b[wn + j * 16 + l15][lq * 8];

#pragma unroll
        for (int i = 0; i < 2; ++i)
#pragma unroll
            for (int j = 0; j < 4; ++j)
                acc[i][j] = __builtin_amdgcn_mfma_f32_16x16x32_bf16(af[i], bfr[j], acc[i][j], 0, 0, 0);
        __syncthreads();
    }

#pragma unroll
    for (int i = 0; i < 2; ++i)
#pragma unroll
        for (int j = 0; j < 4; ++j)
#pragma unroll
            for (int r = 0; r < 4; ++r) {
                int row = bm + wm + i * 16 + lq * 4 + r;
                int col = bn + wn + j * 16 + l15;
                float v = acc[i][j][r];
                v = fmaxf(v + bias[col], 0.0f) + bf2f(resid[(size_t)row * N + col]);
                Cf[(size_t)row * N + col] = v;
            }
}

// ---------------------------------------------------------------------------
// Flash attention v6: equal work PER WAVE via parity split-K.
// Block = 2 waves, tile pair {bx, 127-bx}. Wave w processes chunk indices
// kt ≡ w (mod 2) of BOTH tiles -> every wave in the grid does ~(nkbA+nkbB)/2
// ≈ 16-17 chunks. No-max softmax partials are ADDITIVE (no rescale), so the
// two parity-halves combine by simple o/lsum addition through LDS.
// Order per wave: partner's tile first (partial -> comb LDS), own tile,
// syncthreads, add partner partial, reduce lsum, write y.
// Pipelined stride-2 K prefetch (compile-time buffers), deferred PV, V loads
// issued before K-next so PV's vmcnt wait doesn't drain the K prefetch.
// ---------------------------------------------------------------------------
#define ATTN_STEP2(KFC, KFN)                                                      \
    {                                                                             \
        const int kc0_ = kt << 6;                                                 \
        if (kt > kt0) {                                                           \
            const int pc0_ = kc0_ - 128;                                          \
            _Pragma("unroll")                                                     \
            for (int kc = 0; kc < 2; ++kc)                                        \
                _Pragma("unroll")                                                 \
                for (int n = 0; n < 4; ++n)                                       \
                    vf[kc * 4 + n] = *(const short8*)&vtp[                        \
                        (size_t)(n * 16 + l15) * T + pc0_ + kc * 32 + lq * 8];    \
        }                                                                         \
        if (kt + 2 < nkb) {                                                       \
            const int nc0_ = kc0_ + 128;                                          \
            _Pragma("unroll")                                                     \
            for (int t2 = 0; t2 < 4; ++t2)                                        \
                _Pragma("unroll")                                                 \
                for (int c = 0; c < 2; ++c)                                       \
                    KFN[t2 * 2 + c] = *(const short8*)&kp[                        \
                        (size_t)(nc0_ + t2 * 16 + l15) * S3 + c * 32 + lq * 8];   \
        }                                                                         \
        floatx4 s_[4];                                                            \
        _Pragma("unroll")                                                         \
        for (int t2 = 0; t2 < 4; ++t2) {                                          \
            floatx4 sa_ = (floatx4)0.0f;                                          \
            sa_ = __builtin_amdgcn_mfma_f32_16x16x32_bf16(aq[0], KFC[t2 * 2 + 0], sa_, 0, 0, 0); \
            sa_ = __builtin_amdgcn_mfma_f32_16x16x32_bf16(aq[1], KFC[t2 * 2 + 1], sa_, 0, 0, 0); \
            s_[t2] = sa_;                                                         \
        }                                                                         \
        const bool partial_ = (kc0_ + 63 > qt);                                   \
        _Pragma("unroll")                                                         \
        for (int t2 = 0; t2 < 4; ++t2)                                            \
            _Pragma("unroll")                                                     \
            for (int r = 0; r < 4; ++r) {                                         \
                float p_;                                                         \
                if (partial_) {                                                   \
                    int colg_ = kc0_ + t2 * 16 + l15;                             \
                    int rowg_ = qt + lq * 4 + r;                                  \
                    p_ = (colg_ <= rowg_) ? EXP2F(s_[t2][r] * c2) : 0.0f;         \
                } else {                                                          \
                    p_ = EXP2F(s_[t2][r] * c2);                                   \
                }                                                                 \
                lsum[r] += p_;                                                    \
                lds_p[wave][pb][lq * 4 + r][t2 * 16 + l15] = f2bf(p_);            \
            }                                                                     \
        if (kt > kt0) {                                                           \
            _Pragma("unroll")                                                     \
            for (int kc = 0; kc < 2; ++kc) {                                      \
                short8 ap_ = *(const short8*)&lds_p[wave][pb ^ 1][l15][kc * 32 + lq * 8]; \
                _Pragma("unroll")                                                 \
                for (int n = 0; n < 4; ++n)                                       \
                    o[n] = __builtin_amdgcn_mfma_f32_16x16x32_bf16(ap_, vf[kc * 4 + n], o[n], 0, 0, 0); \
            }                                                                     \
        }                                                                         \
    }

#define ATTN_TILE()                                                               \
    {                                                                             \
        const int nkb = (qt >> 6) + 1;                                            \
        if (kt0 < nkb) {                                                          \
            short8 kfA[8], kfB[8], vf[8];                                         \
            {                                                                     \
                const int kc0_ = kt0 << 6;                                        \
                _Pragma("unroll")                                                 \
                for (int t2 = 0; t2 < 4; ++t2)                                    \
                    _Pragma("unroll")                                             \
                    for (int c = 0; c < 2; ++c)                                   \
                        kfA[t2 * 2 + c] = *(const short8*)&kp[                    \
                            (size_t)(kc0_ + t2 * 16 + l15) * S3 + c * 32 + lq * 8]; \
            }                                                                     \
            int kt = kt0, pb = 0;                                                 \
            while (true) {                                                        \
                ATTN_STEP2(kfA, kfB);                                             \
                kt += 2; pb ^= 1;                                                 \
                if (kt >= nkb) break;                                             \
                ATTN_STEP2(kfB, kfA);                                             \
                kt += 2; pb ^= 1;                                                 \
                if (kt >= nkb) break;                                             \
            }                                                                     \
            /* tail PV for chunk kt-2; its P is in lds_p[wave][pb^1] */           \
            {                                                                     \
                const int pc0_ = (kt - 2) << 6;                                   \
                _Pragma("unroll")                                                 \
                for (int kc = 0; kc < 2; ++kc)                                    \
                    _Pragma("unroll")                                             \
                    for (int n = 0; n < 4; ++n)                                   \
                        vf[kc * 4 + n] = *(const short8*)&vtp[                    \
                            (size_t)(n * 16 + l15) * T + pc0_ + kc * 32 + lq * 8]; \
                _Pragma("unroll")                                                 \
                for (int kc = 0; kc < 2; ++kc) {                                  \
                    short8 ap_ = *(const short8*)&lds_p[wave][pb ^ 1][l15][kc * 32 + lq * 8]; \
                    _Pragma("unroll")                                             \
                    for (int n = 0; n < 4; ++n)                                   \
                        o[n] = __builtin_amdgcn_mfma_f32_16x16x32_bf16(ap_, vf[kc * 4 + n], o[n], 0, 0, 0); \
                }                                                                 \
            }                                                                     \
        }                                                                         \
    }

__global__ __launch_bounds__(128) void attn6_k(
    const u16* __restrict__ qkv, const u16* __restrict__ vt,
    const float* __restrict__ xf, u16* __restrict__ y, int T, int E) {
    __shared__ u16 lds_p[2][2][16][72];     // [wave][buf][row][col(64 used)]
    __shared__ float comb[2][64][21];       // [wave][lane][16 o + 4 lsum], pad 21

    const int tid = threadIdx.x;
    const int lane = tid & 63, wave = tid >> 6;
    const int l15 = lane & 15, lq = lane >> 4;
    const int bh = blockIdx.y;
    const int b = bh >> 4, h = bh & 15;
    const int bx = blockIdx.x;                       // 0..63
    const int tileOwn = wave ? (127 - bx) : bx;
    const int tileFirst = wave ? bx : (127 - bx);
    const int kt0 = wave;                            // chunk parity
    const int S3 = 3 * E;

    const u16* qp = qkv + (size_t)b * T * S3 + (size_t)h * 64;
    const u16* kp = qp + E;
    const u16* vtp = vt + (size_t)bh * 64 * T;       // [64][T]

    const float c2 = 0.04508422f;  // log2(e)/32

    short8 aq[2];
    floatx4 o[4];
    float lsum[4];

    // ---- phase 1: partner-combined tile; partial -> comb[wave] ----
    {
        int qt = tileFirst * 16;
#pragma unroll
        for (int c = 0; c < 2; ++c)
            aq[c] = *(const short8*)&qp[(size_t)(qt + l15) * S3 + c * 32 + lq * 8];
#pragma unroll
        for (int n = 0; n < 4; ++n) o[n] = (floatx4)0.0f;
#pragma unroll
        for (int r = 0; r < 4; ++r) lsum[r] = 0.0f;

        ATTN_TILE();

#pragma unroll
        for (int n = 0; n < 4; ++n)
#pragma unroll
            for (int r = 0; r < 4; ++r) comb[wave][lane][n * 4 + r] = o[n][r];
#pragma unroll
        for (int r = 0; r < 4; ++r) comb[wave][lane][16 + r] = lsum[r];
    }

    // ---- phase 2: own tile ----
    {
        int qt = tileOwn * 16;
#pragma unroll
        for (int c = 0; c < 2; ++c)
            aq[c] = *(const short8*)&qp[(size_t)(qt + l15) * S3 + c * 32 + lq * 8];
#pragma unroll
        for (int n = 0; n < 4; ++n) o[n] = (floatx4)0.0f;
#pragma unroll
        for (int r = 0; r < 4; ++r) lsum[r] = 0.0f;

        ATTN_TILE();

        __syncthreads();  // partner's phase-1 partial is in comb[wave^1]

#pragma unroll
        for (int n = 0; n < 4; ++n)
#pragma unroll
            for (int r = 0; r < 4; ++r) o[n][r] += comb[wave ^ 1][lane][n * 4 + r];
#pragma unroll
        for (int r = 0; r < 4; ++r) lsum[r] += comb[wave ^ 1][lane][16 + r];

        // row-sum reduction across the 16-lane groups
#pragma unroll
        for (int r = 0; r < 4; ++r) {
#pragma unroll
            for (int msk = 1; msk < 16; msk <<= 1) lsum[r] += __shfl_xor(lsum[r], msk, 64);
        }

        // epilogue: y = x + O/l (bf16 out, f32 residual in)
        const float* xp = xf + (size_t)b * T * E + (size_t)h * 64;
        u16* yp = y + (size_t)b * T * E + (size_t)h * 64;
        float rl[4];
#pragma unroll
        for (int r = 0; r < 4; ++r) rl[r] = 1.0f / lsum[r];
#pragma unroll
        for (int n = 0; n < 4; ++n)
#pragma unroll
            for (int r = 0; r < 4; ++r) {
                int rowg = qt + lq * 4 + r;
                int col = n * 16 + l15;
                float val = o[n][r] * rl[r];
                float res = xp[(size_t)rowg * E + col];
                yp[(size_t)rowg * E + col] = f2bf(res + val);
            }
    }
}

// ---------------------------------------------------------------------------
extern "C" void kernel_launch(void* const* d_in, const int* in_sizes, int n_in,
                              void* d_out, int out_size, void* d_ws, size_t ws_size,
                              hipStream_t stream) {
    const int B = 2, T = 2048, E = 1024;
    const int M = B * T;  // 4096

    const float* x  = (const float*)d_in[0];
    const float* Wq = (const float*)d_in[1];
    const float* Wk = (const float*)d_in[2];
    const float* Wv = (const float*)d_in[3];
    const float* Wf = (const float*)d_in[4];
    const float* bf = (const float*)d_in[5];
    float* out = (float*)d_out;

    u16* ws = (u16*)d_ws;
    const size_t WN = (size_t)E * E;      // 1M elems per weight
    const size_t XN = (size_t)M * E;      // 4M elems per activation
    u16* Wqkv = ws;                        // [3E][E] fused transposed weights
    u16* WfT  = ws + 3 * WN;
    u16* xb   = ws + 4 * WN;               // aliased by vt after QKV GEMM
    u16* qkv  = ws + 4 * WN + XN;          // [M][3E] = 3*XN elems
    u16* yb   = ws + 4 * WN + 4 * XN;
    u16* vt   = xb;                        // BH*64*T = XN elems

    conv_transpose_k<<<dim3(E / 32, E / 32, 4), dim3(32, 32), 0, stream>>>(
        Wq, Wk, Wv, Wf, Wqkv, Wqkv + WN, Wqkv + 2 * WN, WfT, E);
    conv_k<<<(int)(XN / 1024), 256, 0, stream>>>(x, xb, (int)XN);

    // fused QKV projection: [M,E] @ [E,3E] -> [M,3E]
    gemm_bt<<<dim3(M / 128, 3 * E / 128), 256, 0, stream>>>(xb, Wqkv, qkv, M, 3 * E, E);

    vtrans_k<<<dim3(T / 32, 2, B * 16), dim3(32, 32), 0, stream>>>(qkv, vt, T, E);

    // 64 tile-pairs x 32 (b,h); 2 waves/block, parity split-K per wave
    attn6_k<<<dim3(64, B * 16), 128, 0, stream>>>(qkv, vt, x, yb, T, E);

    // FF: out = yb + relu(yb @ Wf + bf)
    gemm64_bt<<<dim3(M / 64, E / 128), 256, 0, stream>>>(yb, WfT, out, bf, yb, M, E, E);
}

// Round 9
// 289.068 us; speedup vs baseline: 1.4672x; 1.0002x over previous
//
#include <hip/hip_runtime.h>
#include <cstdint>
#include <cstddef>

typedef unsigned short u16;
typedef short short8 __attribute__((ext_vector_type(8)));
typedef float floatx4 __attribute__((ext_vector_type(4)));

__device__ __forceinline__ float bf2f(u16 u) {
    union { unsigned int i; float f; } v; v.i = ((unsigned int)u) << 16; return v.f;
}
__device__ __forceinline__ u16 f2bf(float f) {
    union { float f; unsigned int i; } v; v.f = f;
    unsigned int u = v.i;
    return (u16)((u + 0x7fffu + ((u >> 16) & 1u)) >> 16);
}

#if __has_builtin(__builtin_amdgcn_exp2f)
#define EXP2F(x) __builtin_amdgcn_exp2f(x)
#else
#define EXP2F(x) exp2f(x)
#endif

// async global->LDS, 16B per lane; LDS dest = wave-uniform base + lane*16
__device__ __forceinline__ void gload_lds16(const u16* g, void* lds_wave_base) {
    __builtin_amdgcn_global_load_lds(
        (__attribute__((address_space(1))) void*)g,
        (__attribute__((address_space(3))) void*)lds_wave_base,
        16, 0, 0);
}

// ---------------------------------------------------------------------------
// Convert+transpose 4 weight matrices (E x E, f32) -> bf16. Wt[n][k]=W[k][n].
// ---------------------------------------------------------------------------
__global__ void conv_transpose_k(const float* __restrict__ w0, const float* __restrict__ w1,
                                 const float* __restrict__ w2, const float* __restrict__ w3,
                                 u16* __restrict__ o0, u16* __restrict__ o1,
                                 u16* __restrict__ o2, u16* __restrict__ o3, int n) {
    __shared__ float t[32][33];
    const float* w; u16* o;
    switch (blockIdx.z) {
        case 0: w = w0; o = o0; break;
        case 1: w = w1; o = o1; break;
        case 2: w = w2; o = o2; break;
        default: w = w3; o = o3; break;
    }
    int tx = threadIdx.x, ty = threadIdx.y;
    int x0 = blockIdx.x * 32, y0 = blockIdx.y * 32;
    t[ty][tx] = w[(size_t)(y0 + ty) * n + x0 + tx];
    __syncthreads();
    o[(size_t)(x0 + ty) * n + y0 + tx] = f2bf(t[tx][ty]);
}

// ---------------------------------------------------------------------------
// Convert f32 -> bf16, vectorized.
// ---------------------------------------------------------------------------
__global__ void conv_k(const float* __restrict__ in, u16* __restrict__ out, int n) {
    int i = (blockIdx.x * blockDim.x + threadIdx.x) * 4;
    if (i >= n) return;
    float4 v = *(const float4*)&in[i];
    ushort4 o;
    o.x = f2bf(v.x); o.y = f2bf(v.y); o.z = f2bf(v.z); o.w = f2bf(v.w);
    *(ushort4*)&out[i] = o;
}

// ---------------------------------------------------------------------------
// Per-head V transpose from fused qkv buffer (row stride 3E, V at col 2E):
// vt[(b*16+h)*64 + d][t] = qkv[(b*T+t)*3E + 2E + h*64 + d]
// ---------------------------------------------------------------------------
__global__ void vtrans_k(const u16* __restrict__ qkv, u16* __restrict__ vt, int T, int E) {
    __shared__ u16 t[32][33];
    int bh = blockIdx.z;
    int b = bh >> 4, h = bh & 15;
    int t0 = blockIdx.x * 32, d0 = blockIdx.y * 32;
    int tx = threadIdx.x, ty = threadIdx.y;
    t[ty][tx] = qkv[(size_t)(b * T + t0 + ty) * (3 * E) + 2 * E + h * 64 + d0 + tx];
    __syncthreads();
    vt[((size_t)bh * 64 + d0 + ty) * T + t0 + tx] = t[tx][ty];
}

// ---------------------------------------------------------------------------
// C[M,N] = A[M,K] @ Bt[N,K]^T, bf16 in, f32 accum, bf16 out.
// 128x128 tile, BK=32, 4 waves x (4x4) 16x16x32 MFMA. global_load_lds staging.
// ---------------------------------------------------------------------------
__global__ __launch_bounds__(256) void gemm_bt(
    const u16* __restrict__ A, const u16* __restrict__ Bt, u16* __restrict__ Cb,
    int M, int N, int K) {
    __shared__ u16 lds_a[128][32];
    __shared__ u16 lds_b[128][32];

    const int tid = threadIdx.x;
    const int lane = tid & 63, wave = tid >> 6;
    const int wm = (wave >> 1) * 64, wn = (wave & 1) * 64;
    const int bm = blockIdx.x * 128, bn = blockIdx.y * 128;
    const int l15 = lane & 15, lq = lane >> 4;

    floatx4 acc[4][4];
#pragma unroll
    for (int i = 0; i < 4; ++i)
#pragma unroll
        for (int j = 0; j < 4; ++j) acc[i][j] = (floatx4)0.0f;

    for (int k0 = 0; k0 < K; k0 += 32) {
#pragma unroll
        for (int it = 0; it < 2; ++it) {
            int idx = it * 256 + tid;        // 0..511
            int row = idx >> 2;              // 0..127
            int c8 = (idx & 3) * 8;          // 0,8,16,24
            size_t ldsoff = (size_t)(it * 256 + wave * 64) * 16;  // bytes, wave-uniform
            gload_lds16(&A[(size_t)(bm + row) * K + k0 + c8], (char*)&lds_a[0][0] + ldsoff);
            gload_lds16(&Bt[(size_t)(bn + row) * K + k0 + c8], (char*)&lds_b[0][0] + ldsoff);
        }
        __syncthreads();

        short8 af[4], bfr[4];
#pragma unroll
        for (int i = 0; i < 4; ++i) af[i] = *(const short8*)&lds_a[wm + i * 16 + l15][lq * 8];
#pragma unroll
        for (int j = 0; j < 4; ++j) bfr[j] = *(const short8*)&lds_b[wn + j * 16 + l15][lq * 8];

#pragma unroll
        for (int i = 0; i < 4; ++i)
#pragma unroll
            for (int j = 0; j < 4; ++j)
                acc[i][j] = __builtin_amdgcn_mfma_f32_16x16x32_bf16(af[i], bfr[j], acc[i][j], 0, 0, 0);
        __syncthreads();
    }

#pragma unroll
    for (int i = 0; i < 4; ++i)
#pragma unroll
        for (int j = 0; j < 4; ++j)
#pragma unroll
            for (int r = 0; r < 4; ++r) {
                int row = bm + wm + i * 16 + lq * 4 + r;
                int col = bn + wn + j * 16 + l15;
                Cb[(size_t)row * N + col] = f2bf(acc[i][j][r]);
            }
}

// ---------------------------------------------------------------------------
// FF GEMM: 64x128 tile. Cf (f32) = bf2f(resid) + relu(acc + bias[col]).
// ---------------------------------------------------------------------------
__global__ __launch_bounds__(256) void gemm64_bt(
    const u16* __restrict__ A, const u16* __restrict__ Bt, float* __restrict__ Cf,
    const float* __restrict__ bias, const u16* __restrict__ resid,
    int M, int N, int K) {
    __shared__ u16 lds_a[64][32];
    __shared__ u16 lds_b[128][32];

    const int tid = threadIdx.x;
    const int lane = tid & 63, wave = tid >> 6;
    const int wm = (wave >> 1) * 32, wn = (wave & 1) * 64;
    const int bm = blockIdx.x * 64, bn = blockIdx.y * 128;
    const int l15 = lane & 15, lq = lane >> 4;

    floatx4 acc[2][4];
#pragma unroll
    for (int i = 0; i < 2; ++i)
#pragma unroll
        for (int j = 0; j < 4; ++j) acc[i][j] = (floatx4)0.0f;

    for (int k0 = 0; k0 < K; k0 += 32) {
        {
            int row = tid >> 2;              // 0..63
            int c8 = (tid & 3) * 8;
            size_t ldsoff = (size_t)(wave * 64) * 16;
            gload_lds16(&A[(size_t)(bm + row) * K + k0 + c8], (char*)&lds_a[0][0] + ldsoff);
        }
#pragma unroll
        for (int it = 0; it < 2; ++it) {
            int idx = it * 256 + tid;
            int row = idx >> 2;              // 0..127
            int c8 = (idx & 3) * 8;
            size_t ldsoff = (size_t)(it * 256 + wave * 64) * 16;
            gload_lds16(&Bt[(size_t)(bn + row) * K + k0 + c8], (char*)&lds_b[0][0] + ldsoff);
        }
        __syncthreads();

        short8 af[2], bfr[4];
#pragma unroll
        for (int i = 0; i < 2; ++i) af[i] = *(const short8*)&lds_a[wm + i * 16 + l15][lq * 8];
#pragma unroll
        for (int j = 0; j < 4; ++j) bfr[j] = *(const short8*)&lds_b[wn + j * 16 + l15][lq * 8];

#pragma unroll
        for (int i = 0; i < 2; ++i)
#pragma unroll
            for (int j = 0; j < 4; ++j)
                acc[i][j] = __builtin_amdgcn_mfma_f32_16x16x32_bf16(af[i], bfr[j], acc[i][j], 0, 0, 0);
        __syncthreads();
    }

#pragma unroll
    for (int i = 0; i < 2; ++i)
#pragma unroll
        for (int j = 0; j < 4; ++j)
#pragma unroll
            for (int r = 0; r < 4; ++r) {
                int row = bm + wm + i * 16 + lq * 4 + r;
                int col = bn + wn + j * 16 + l15;
                float v = acc[i][j][r];
                v = fmaxf(v + bias[col], 0.0f) + bf2f(resid[(size_t)row * N + col]);
                Cf[(size_t)row * N + col] = v;
            }
}

// ---------------------------------------------------------------------------
// Flash attention v7 = v6 + XCD-affinity grid swizzle + nontemporal x reads.
// Grid is (bh, pair): with linear-id round-robin XCD dispatch and gridDim.x
// = 32 ≡ 0 (mod 8), every block of head bh lands on XCD bh%8 -> each XCD's
// 4 MB L2 holds K+V of exactly 4 heads (~2 MB) instead of thrashing across
// all 32. x (32 MB f32, single-use) is read nontemporally to avoid evicting
// K/V. Everything else identical to v6 (parity split-K, additive no-max
// softmax partials, compile-time-alternated K prefetch).
// ---------------------------------------------------------------------------
#define ATTN_STEP2(KFC, KFN)                                                      \
    {                                                                             \
        const int kc0_ = kt << 6;                                                 \
        if (kt > kt0) {                                                           \
            const int pc0_ = kc0_ - 128;                                          \
            _Pragma("unroll")                                                     \
            for (int kc = 0; kc < 2; ++kc)                                        \
                _Pragma("unroll")                                                 \
                for (int n = 0; n < 4; ++n)                                       \
                    vf[kc * 4 + n] = *(const short8*)&vtp[                        \
                        (size_t)(n * 16 + l15) * T + pc0_ + kc * 32 + lq * 8];    \
        }                                                                         \
        if (kt + 2 < nkb) {                                                       \
            const int nc0_ = kc0_ + 128;                                          \
            _Pragma("unroll")                                                     \
            for (int t2 = 0; t2 < 4; ++t2)                                        \
                _Pragma("unroll")                                                 \
                for (int c = 0; c < 2; ++c)                                       \
                    KFN[t2 * 2 + c] = *(const short8*)&kp[                        \
                        (size_t)(nc0_ + t2 * 16 + l15) * S3 + c * 32 + lq * 8];   \
        }                                                                         \
        floatx4 s_[4];                                                            \
        _Pragma("unroll")                                                         \
        for (int t2 = 0; t2 < 4; ++t2) {                                          \
            floatx4 sa_ = (floatx4)0.0f;                                          \
            sa_ = __builtin_amdgcn_mfma_f32_16x16x32_bf16(aq[0], KFC[t2 * 2 + 0], sa_, 0, 0, 0); \
            sa_ = __builtin_amdgcn_mfma_f32_16x16x32_bf16(aq[1], KFC[t2 * 2 + 1], sa_, 0, 0, 0); \
            s_[t2] = sa_;                                                         \
        }                                                                         \
        const bool partial_ = (kc0_ + 63 > qt);                                   \
        _Pragma("unroll")                                                         \
        for (int t2 = 0; t2 < 4; ++t2)                                            \
            _Pragma("unroll")                                                     \
            for (int r = 0; r < 4; ++r) {                                         \
                float p_;                                                         \
                if (partial_) {                                                   \
                    int colg_ = kc0_ + t2 * 16 + l15;                             \
                    int rowg_ = qt + lq * 4 + r;                                  \
                    p_ = (colg_ <= rowg_) ? EXP2F(s_[t2][r] * c2) : 0.0f;         \
                } else {                                                          \
                    p_ = EXP2F(s_[t2][r] * c2);                                   \
                }                                                                 \
                lsum[r] += p_;                                                    \
                lds_p[wave][pb][lq * 4 + r][t2 * 16 + l15] = f2bf(p_);            \
            }                                                                     \
        if (kt > kt0) {                                                           \
            _Pragma("unroll")                                                     \
            for (int kc = 0; kc < 2; ++kc) {                                      \
                short8 ap_ = *(const short8*)&lds_p[wave][pb ^ 1][l15][kc * 32 + lq * 8]; \
                _Pragma("unroll")                                                 \
                for (int n = 0; n < 4; ++n)                                       \
                    o[n] = __builtin_amdgcn_mfma_f32_16x16x32_bf16(ap_, vf[kc * 4 + n], o[n], 0, 0, 0); \
            }                                                                     \
        }                                                                         \
    }

#define ATTN_TILE()                                                               \
    {                                                                             \
        const int nkb = (qt >> 6) + 1;                                            \
        if (kt0 < nkb) {                                                          \
            short8 kfA[8], kfB[8], vf[8];                                         \
            {                                                                     \
                const int kc0_ = kt0 << 6;                                        \
                _Pragma("unroll")                                                 \
                for (int t2 = 0; t2 < 4; ++t2)                                    \
                    _Pragma("unroll")                                             \
                    for (int c = 0; c < 2; ++c)                                   \
                        kfA[t2 * 2 + c] = *(const short8*)&kp[                    \
                            (size_t)(kc0_ + t2 * 16 + l15) * S3 + c * 32 + lq * 8]; \
            }                                                                     \
            int kt = kt0, pb = 0;                                                 \
            while (true) {                                                        \
                ATTN_STEP2(kfA, kfB);                                             \
                kt += 2; pb ^= 1;                                                 \
                if (kt >= nkb) break;                                             \
                ATTN_STEP2(kfB, kfA);                                             \
                kt += 2; pb ^= 1;                                                 \
                if (kt >= nkb) break;                                             \
            }                                                                     \
            /* tail PV for chunk kt-2; its P is in lds_p[wave][pb^1] */           \
            {                                                                     \
                const int pc0_ = (kt - 2) << 6;                                   \
                _Pragma("unroll")                                                 \
                for (int kc = 0; kc < 2; ++kc)                                    \
                    _Pragma("unroll")                                             \
                    for (int n = 0; n < 4; ++n)                                   \
                        vf[kc * 4 + n] = *(const short8*)&vtp[                    \
                            (size_t)(n * 16 + l15) * T + pc0_ + kc * 32 + lq * 8]; \
                _Pragma("unroll")                                                 \
                for (int kc = 0; kc < 2; ++kc) {                                  \
                    short8 ap_ = *(const short8*)&lds_p[wave][pb ^ 1][l15][kc * 32 + lq * 8]; \
                    _Pragma("unroll")                                             \
                    for (int n = 0; n < 4; ++n)                                   \
                        o[n] = __builtin_amdgcn_mfma_f32_16x16x32_bf16(ap_, vf[kc * 4 + n], o[n], 0, 0, 0); \
                }                                                                 \
            }                                                                     \
        }                                                                         \
    }

__global__ __launch_bounds__(128) void attn7_k(
    const u16* __restrict__ qkv, const u16* __restrict__ vt,
    const float* __restrict__ xf, u16* __restrict__ y, int T, int E) {
    __shared__ u16 lds_p[2][2][16][72];     // [wave][buf][row][col(64 used)]
    __shared__ float comb[2][64][21];       // [wave][lane][16 o + 4 lsum], pad 21

    const int tid = threadIdx.x;
    const int lane = tid & 63, wave = tid >> 6;
    const int l15 = lane & 15, lq = lane >> 4;
    const int bh = blockIdx.x;                       // XCD affinity: bh%8 fixed per XCD
    const int b = bh >> 4, h = bh & 15;
    const int bx = blockIdx.y;                       // 0..63 tile pair
    const int tileOwn = wave ? (127 - bx) : bx;
    const int tileFirst = wave ? bx : (127 - bx);
    const int kt0 = wave;                            // chunk parity
    const int S3 = 3 * E;

    const u16* qp = qkv + (size_t)b * T * S3 + (size_t)h * 64;
    const u16* kp = qp + E;
    const u16* vtp = vt + (size_t)bh * 64 * T;       // [64][T]

    const float c2 = 0.04508422f;  // log2(e)/32

    short8 aq[2];
    floatx4 o[4];
    float lsum[4];

    // ---- phase 1: partner-combined tile; partial -> comb[wave] ----
    {
        int qt = tileFirst * 16;
#pragma unroll
        for (int c = 0; c < 2; ++c)
            aq[c] = *(const short8*)&qp[(size_t)(qt + l15) * S3 + c * 32 + lq * 8];
#pragma unroll
        for (int n = 0; n < 4; ++n) o[n] = (floatx4)0.0f;
#pragma unroll
        for (int r = 0; r < 4; ++r) lsum[r] = 0.0f;

        ATTN_TILE();

#pragma unroll
        for (int n = 0; n < 4; ++n)
#pragma unroll
            for (int r = 0; r < 4; ++r) comb[wave][lane][n * 4 + r] = o[n][r];
#pragma unroll
        for (int r = 0; r < 4; ++r) comb[wave][lane][16 + r] = lsum[r];
    }

    // ---- phase 2: own tile ----
    {
        int qt = tileOwn * 16;
#pragma unroll
        for (int c = 0; c < 2; ++c)
            aq[c] = *(const short8*)&qp[(size_t)(qt + l15) * S3 + c * 32 + lq * 8];
#pragma unroll
        for (int n = 0; n < 4; ++n) o[n] = (floatx4)0.0f;
#pragma unroll
        for (int r = 0; r < 4; ++r) lsum[r] = 0.0f;

        ATTN_TILE();

        __syncthreads();  // partner's phase-1 partial is in comb[wave^1]

#pragma unroll
        for (int n = 0; n < 4; ++n)
#pragma unroll
            for (int r = 0; r < 4; ++r) o[n][r] += comb[wave ^ 1][lane][n * 4 + r];
#pragma unroll
        for (int r = 0; r < 4; ++r) lsum[r] += comb[wave ^ 1][lane][16 + r];

        // row-sum reduction across the 16-lane groups
#pragma unroll
        for (int r = 0; r < 4; ++r) {
#pragma unroll
            for (int msk = 1; msk < 16; msk <<= 1) lsum[r] += __shfl_xor(lsum[r], msk, 64);
        }

        // epilogue: y = x + O/l (bf16 out, f32 residual in, nontemporal x)
        const float* xp = xf + (size_t)b * T * E + (size_t)h * 64;
        u16* yp = y + (size_t)b * T * E + (size_t)h * 64;
        float rl[4];
#pragma unroll
        for (int r = 0; r < 4; ++r) rl[r] = 1.0f / lsum[r];
#pragma unroll
        for (int n = 0; n < 4; ++n)
#pragma unroll
            for (int r = 0; r < 4; ++r) {
                int rowg = qt + lq * 4 + r;
                int col = n * 16 + l15;
                float val = o[n][r] * rl[r];
                float res = __builtin_nontemporal_load(xp + (size_t)rowg * E + col);
                yp[(size_t)rowg * E + col] = f2bf(res + val);
            }
    }
}

// ---------------------------------------------------------------------------
extern "C" void kernel_launch(void* const* d_in, const int* in_sizes, int n_in,
                              void* d_out, int out_size, void* d_ws, size_t ws_size,
                              hipStream_t stream) {
    const int B = 2, T = 2048, E = 1024;
    const int M = B * T;  // 4096

    const float* x  = (const float*)d_in[0];
    const float* Wq = (const float*)d_in[1];
    const float* Wk = (const float*)d_in[2];
    const float* Wv = (const float*)d_in[3];
    const float* Wf = (const float*)d_in[4];
    const float* bf = (const float*)d_in[5];
    float* out = (float*)d_out;

    u16* ws = (u16*)d_ws;
    const size_t WN = (size_t)E * E;      // 1M elems per weight
    const size_t XN = (size_t)M * E;      // 4M elems per activation
    u16* Wqkv = ws;                        // [3E][E] fused transposed weights
    u16* WfT  = ws + 3 * WN;
    u16* xb   = ws + 4 * WN;               // aliased by vt after QKV GEMM
    u16* qkv  = ws + 4 * WN + XN;          // [M][3E] = 3*XN elems
    u16* yb   = ws + 4 * WN + 4 * XN;
    u16* vt   = xb;                        // BH*64*T = XN elems

    conv_transpose_k<<<dim3(E / 32, E / 32, 4), dim3(32, 32), 0, stream>>>(
        Wq, Wk, Wv, Wf, Wqkv, Wqkv + WN, Wqkv + 2 * WN, WfT, E);
    conv_k<<<(int)(XN / 1024), 256, 0, stream>>>(x, xb, (int)XN);

    // fused QKV projection: [M,E] @ [E,3E] -> [M,3E]
    gemm_bt<<<dim3(M / 128, 3 * E / 128), 256, 0, stream>>>(xb, Wqkv, qkv, M, 3 * E, E);

    vtrans_k<<<dim3(T / 32, 2, B * 16), dim3(32, 32), 0, stream>>>(qkv, vt, T, E);

    // grid (bh, pair): all blocks of one head land on one XCD (bh%8)
    attn7_k<<<dim3(B * 16, 64), 128, 0, stream>>>(qkv, vt, x, yb, T, E);

    // FF: out = yb + relu(yb @ Wf + bf)
    gemm64_bt<<<dim3(M / 64, E / 128), 256, 0, stream>>>(yb, WfT, out, bf, yb, M, E, E);
}

// Round 11
// 219.916 us; speedup vs baseline: 1.9285x; 1.3144x over previous
//
#include <hip/hip_runtime.h>
#include <cstdint>
#include <cstddef>

typedef unsigned short u16;
typedef short short8 __attribute__((ext_vector_type(8)));
typedef float floatx4 __attribute__((ext_vector_type(4)));

__device__ __forceinline__ float bf2f(u16 u) {
    union { unsigned int i; float f; } v; v.i = ((unsigned int)u) << 16; return v.f;
}
__device__ __forceinline__ u16 f2bf(float f) {
    union { float f; unsigned int i; } v; v.f = f;
    unsigned int u = v.i;
    return (u16)((u + 0x7fffu + ((u >> 16) & 1u)) >> 16);
}

#if __has_builtin(__builtin_amdgcn_exp2f)
#define EXP2F(x) __builtin_amdgcn_exp2f(x)
#else
#define EXP2F(x) exp2f(x)
#endif

// async global->LDS, 16B per lane; LDS dest = wave-uniform base + lane*16
__device__ __forceinline__ void gload_lds16(const u16* g, void* lds_wave_base) {
    __builtin_amdgcn_global_load_lds(
        (__attribute__((address_space(1))) void*)g,
        (__attribute__((address_space(3))) void*)lds_wave_base,
        16, 0, 0);
}

// ---------------------------------------------------------------------------
// Convert+transpose 4 weight matrices (E x E, f32) -> bf16. Wt[n][k]=W[k][n].
// ---------------------------------------------------------------------------
__global__ void conv_transpose_k(const float* __restrict__ w0, const float* __restrict__ w1,
                                 const float* __restrict__ w2, const float* __restrict__ w3,
                                 u16* __restrict__ o0, u16* __restrict__ o1,
                                 u16* __restrict__ o2, u16* __restrict__ o3, int n) {
    __shared__ float t[32][33];
    const float* w; u16* o;
    switch (blockIdx.z) {
        case 0: w = w0; o = o0; break;
        case 1: w = w1; o = o1; break;
        case 2: w = w2; o = o2; break;
        default: w = w3; o = o3; break;
    }
    int tx = threadIdx.x, ty = threadIdx.y;
    int x0 = blockIdx.x * 32, y0 = blockIdx.y * 32;
    t[ty][tx] = w[(size_t)(y0 + ty) * n + x0 + tx];
    __syncthreads();
    o[(size_t)(x0 + ty) * n + y0 + tx] = f2bf(t[tx][ty]);
}

// ---------------------------------------------------------------------------
// Convert f32 -> bf16, vectorized.
// ---------------------------------------------------------------------------
__global__ void conv_k(const float* __restrict__ in, u16* __restrict__ out, int n) {
    int i = (blockIdx.x * blockDim.x + threadIdx.x) * 4;
    if (i >= n) return;
    float4 v = *(const float4*)&in[i];
    ushort4 o;
    o.x = f2bf(v.x); o.y = f2bf(v.y); o.z = f2bf(v.z); o.w = f2bf(v.w);
    *(ushort4*)&out[i] = o;
}

// ---------------------------------------------------------------------------
// V pack: per-head, per-64-chunk dense blocks for coalesced DMA staging.
// vpack[bh][kblk][d(64)][tloc(64)] = qkv[(b*T + kblk*64+tloc)*3E + 2E + h*64 + d]
// grid (T/32, 2, BH), block (32,32)
// ---------------------------------------------------------------------------
__global__ void vpack_k(const u16* __restrict__ qkv, u16* __restrict__ vp, int T, int E) {
    __shared__ u16 t[32][33];
    int bh = blockIdx.z;
    int b = bh >> 4, h = bh & 15;
    int t0 = blockIdx.x * 32, d0 = blockIdx.y * 32;
    int tx = threadIdx.x, ty = threadIdx.y;
    t[ty][tx] = qkv[(size_t)(b * T + t0 + ty) * (3 * E) + 2 * E + h * 64 + d0 + tx];
    __syncthreads();
    int kblk = t0 >> 6, tbase = t0 & 32;
    vp[(((size_t)bh * (T / 64) + kblk) * 64 + d0 + ty) * 64 + tbase + tx] = t[tx][ty];
}

// ---------------------------------------------------------------------------
// K pack (optional, if ws_size permits): dense per-head K.
// kpack[bh][t][d] = qkv[(b*T+t)*3E + E + h*64 + d]. grid (T/32, BH), 256 thr.
// ---------------------------------------------------------------------------
__global__ void kpack_k(const u16* __restrict__ qkv, u16* __restrict__ kp, int T, int E) {
    int bh = blockIdx.y;
    int b = bh >> 4, h = bh & 15;
    int tid = threadIdx.x;
    int t = blockIdx.x * 32 + (tid >> 3);
    int c8 = (tid & 7) * 8;
    *(uint4*)&kp[((size_t)bh * T + t) * 64 + c8] =
        *(const uint4*)&qkv[(size_t)(b * T + t) * (3 * E) + E + h * 64 + c8];
}

// ---------------------------------------------------------------------------
// C[M,N] = A[M,K] @ Bt[N,K]^T, bf16 in, f32 accum, bf16 out.
// 128x128 tile, BK=32, 4 waves x (4x4) 16x16x32 MFMA. global_load_lds staging.
// ---------------------------------------------------------------------------
__global__ __launch_bounds__(256) void gemm_bt(
    const u16* __restrict__ A, const u16* __restrict__ Bt, u16* __restrict__ Cb,
    int M, int N, int K) {
    __shared__ u16 lds_a[128][32];
    __shared__ u16 lds_b[128][32];

    const int tid = threadIdx.x;
    const int lane = tid & 63, wave = tid >> 6;
    const int wm = (wave >> 1) * 64, wn = (wave & 1) * 64;
    const int bm = blockIdx.x * 128, bn = blockIdx.y * 128;
    const int l15 = lane & 15, lq = lane >> 4;

    floatx4 acc[4][4];
#pragma unroll
    for (int i = 0; i < 4; ++i)
#pragma unroll
        for (int j = 0; j < 4; ++j) acc[i][j] = (floatx4)0.0f;

    for (int k0 = 0; k0 < K; k0 += 32) {
#pragma unroll
        for (int it = 0; it < 2; ++it) {
            int idx = it * 256 + tid;        // 0..511
            int row = idx >> 2;              // 0..127
            int c8 = (idx & 3) * 8;          // 0,8,16,24
            size_t ldsoff = (size_t)(it * 256 + wave * 64) * 16;  // bytes, wave-uniform
            gload_lds16(&A[(size_t)(bm + row) * K + k0 + c8], (char*)&lds_a[0][0] + ldsoff);
            gload_lds16(&Bt[(size_t)(bn + row) * K + k0 + c8], (char*)&lds_b[0][0] + ldsoff);
        }
        __syncthreads();

        short8 af[4], bfr[4];
#pragma unroll
        for (int i = 0; i < 4; ++i) af[i] = *(const short8*)&lds_a[wm + i * 16 + l15][lq * 8];
#pragma unroll
        for (int j = 0; j < 4; ++j) bfr[j] = *(const short8*)&lds_b[wn + j * 16 + l15][lq * 8];

#pragma unroll
        for (int i = 0; i < 4; ++i)
#pragma unroll
            for (int j = 0; j < 4; ++j)
                acc[i][j] = __builtin_amdgcn_mfma_f32_16x16x32_bf16(af[i], bfr[j], acc[i][j], 0, 0, 0);
        __syncthreads();
    }

#pragma unroll
    for (int i = 0; i < 4; ++i)
#pragma unroll
        for (int j = 0; j < 4; ++j)
#pragma unroll
            for (int r = 0; r < 4; ++r) {
                int row = bm + wm + i * 16 + lq * 4 + r;
                int col = bn + wn + j * 16 + l15;
                Cb[(size_t)row * N + col] = f2bf(acc[i][j][r]);
            }
}

// ---------------------------------------------------------------------------
// FF GEMM: 64x128 tile. Cf (f32) = bf2f(resid) + relu(acc + bias[col]).
// ---------------------------------------------------------------------------
__global__ __launch_bounds__(256) void gemm64_bt(
    const u16* __restrict__ A, const u16* __restrict__ Bt, float* __restrict__ Cf,
    const float* __restrict__ bias, const u16* __restrict__ resid,
    int M, int N, int K) {
    __shared__ u16 lds_a[64][32];
    __shared__ u16 lds_b[128][32];

    const int tid = threadIdx.x;
    const int lane = tid & 63, wave = tid >> 6;
    const int wm = (wave >> 1) * 32, wn = (wave & 1) * 64;
    const int bm = blockIdx.x * 64, bn = blockIdx.y * 128;
    const int l15 = lane & 15, lq = lane >> 4;

    floatx4 acc[2][4];
#pragma unroll
    for (int i = 0; i < 2; ++i)
#pragma unroll
        for (int j = 0; j < 4; ++j) acc[i][j] = (floatx4)0.0f;

    for (int k0 = 0; k0 < K; k0 += 32) {
        {
            int row = tid >> 2;              // 0..63
            int c8 = (tid & 3) * 8;
            size_t ldsoff = (size_t)(wave * 64) * 16;
            gload_lds16(&A[(size_t)(bm + row) * K + k0 + c8], (char*)&lds_a[0][0] + ldsoff);
        }
#pragma unroll
        for (int it = 0; it < 2; ++it) {
            int idx = it * 256 + tid;
            int row = idx >> 2;              // 0..127
            int c8 = (idx & 3) * 8;
            size_t ldsoff = (size_t)(it * 256 + wave * 64) * 16;
            gload_lds16(&Bt[(size_t)(bn + row) * K + k0 + c8], (char*)&lds_b[0][0] + ldsoff);
        }
        __syncthreads();

        short8 af[2], bfr[4];
#pragma unroll
        for (int i = 0; i < 2; ++i) af[i] = *(const short8*)&lds_a[wm + i * 16 + l15][lq * 8];
#pragma unroll
        for (int j = 0; j < 4; ++j) bfr[j] = *(const short8*)&lds_b[wn + j * 16 + l15][lq * 8];

#pragma unroll
        for (int i = 0; i < 2; ++i)
#pragma unroll
            for (int j = 0; j < 4; ++j)
                acc[i][j] = __builtin_amdgcn_mfma_f32_16x16x32_bf16(af[i], bfr[j], acc[i][j], 0, 0, 0);
        __syncthreads();
    }

#pragma unroll
    for (int i = 0; i < 2; ++i)
#pragma unroll
        for (int j = 0; j < 4; ++j)
#pragma unroll
            for (int r = 0; r < 4; ++r) {
                int row = bm + wm + i * 16 + lq * 4 + r;
                int col = bn + wn + j * 16 + l15;
                float v = acc[i][j][r];
                v = fmaxf(v + bias[col], 0.0f) + bf2f(resid[(size_t)row * N + col]);
                Cf[(size_t)row * N + col] = v;
            }
}

// ---------------------------------------------------------------------------
// Flash attention v8b: canonical cooperative-LDS structure (m97-style).
// Block = 4 waves = one 64-row Q block. T/64 = 32 q-blocks per (b,h); each
// block handles the causal pair {bx, 31-bx} sequentially -> uniform 33
// chunk-iterations per block. (v8 crashed: used {bx, 63-bx} -> qt up to
// 4080 > T-1 -> OOB page fault.)
// Per iteration: 64x64 K and V chunks staged ONCE per block into LDS via
// global_load_lds (DMA path, XOR-swizzled so ds_read_b128 fragment reads
// are conflict-free), barrier, QK^T -> no-max softmax -> P (wave-private
// LDS) -> PV, barrier.
// ---------------------------------------------------------------------------
__global__ __launch_bounds__(256) void attn8_k(
    const u16* __restrict__ qkv, const u16* __restrict__ kpack, int packed,
    const u16* __restrict__ vpack, const float* __restrict__ xf,
    u16* __restrict__ y, int T, int E) {
    __shared__ u16 kbuf[64 * 64];           // [t][64 d], cols XOR-swizzled
    __shared__ u16 vbuf[64 * 64];           // [d][64 t], cols XOR-swizzled
    __shared__ u16 lds_p[4][16][72];        // wave-private P, 72-pad

    const int tid = threadIdx.x;
    const int lane = tid & 63, wave = tid >> 6;
    const int l15 = lane & 15, lq = lane >> 4;
    const int bh = blockIdx.x;              // grid.x = 32 -> head-per-XCD affinity
    const int b = bh >> 4, h = bh & 15;
    const int bx = blockIdx.y;              // 0..15 -> q-block pair {bx, 31-bx}
    const int S3 = 3 * E;

    const u16* qp = qkv + (size_t)b * T * S3 + (size_t)h * 64;
    const u16* kb;
    int ks;
    if (packed) { kb = kpack + (size_t)bh * T * 64; ks = 64; }
    else        { kb = qp + E;                      ks = S3; }
    const u16* vp = vpack + (size_t)bh * T * 64;    // [T/64][64][64] blocks

    const float c2 = 0.04508422f;  // log2(e)/32
    const int r0 = tid >> 3;            // staging row 0..31
    const int slot = tid & 7;           // staging 16B slot within row
    const int swz0 = ((slot - (r0 & 7)) & 7) * 8;   // source col elems (swizzle)
    const int fsw = (l15 & 7) * 16;     // fragment-read swizzle byte offset

#pragma unroll 1
    for (int p = 0; p < 2; ++p) {
        const int qb = p ? (31 - bx) : bx;          // q-block 0..31
        const int qt = qb * 64 + wave * 16;         // this wave's 16 rows
        const int nkb = qb + 1;

        short8 aq[2];
#pragma unroll
        for (int c = 0; c < 2; ++c)
            aq[c] = *(const short8*)&qp[(size_t)(qt + l15) * S3 + c * 32 + lq * 8];

        floatx4 o[4];
#pragma unroll
        for (int n = 0; n < 4; ++n) o[n] = (floatx4)0.0f;
        float lsum[4];
#pragma unroll
        for (int r = 0; r < 4; ++r) lsum[r] = 0.0f;

#pragma unroll 1
        for (int kt = 0; kt < nkb; ++kt) {
            const int kc0 = kt * 64;

            // ---- cooperative staging: K 8KB + V 8KB per block ----
            gload_lds16(kb + (size_t)(kc0 + r0) * ks + swz0,
                        (char*)kbuf + wave * 1024);
            gload_lds16(kb + (size_t)(kc0 + r0 + 32) * ks + swz0,
                        (char*)kbuf + 4096 + wave * 1024);
            const u16* vchunk = vp + (size_t)kt * 4096;
            gload_lds16(vchunk + (size_t)r0 * 64 + swz0,
                        (char*)vbuf + wave * 1024);
            gload_lds16(vchunk + (size_t)(r0 + 32) * 64 + swz0,
                        (char*)vbuf + 4096 + wave * 1024);
            __syncthreads();

            // ---- S = Q K^T (16 rows x 64 cols) ----
            floatx4 s[4];
#pragma unroll
            for (int t2 = 0; t2 < 4; ++t2) {
                floatx4 sa = (floatx4)0.0f;
#pragma unroll
                for (int c = 0; c < 2; ++c) {
                    int off = (t2 * 16 + l15) * 128 + ((c * 64 + lq * 16 + fsw) & 127);
                    short8 bk = *(const short8*)((const char*)kbuf + off);
                    sa = __builtin_amdgcn_mfma_f32_16x16x32_bf16(aq[c], bk, sa, 0, 0, 0);
                }
                s[t2] = sa;
            }

            // ---- no-max softmax numerator, P -> wave-private LDS ----
            const bool partial = (kt == qb);   // block-uniform: only diagonal chunk
#pragma unroll
            for (int t2 = 0; t2 < 4; ++t2)
#pragma unroll
                for (int r = 0; r < 4; ++r) {
                    float pv;
                    if (partial) {
                        int colg = kc0 + t2 * 16 + l15;
                        int rowg = qt + lq * 4 + r;
                        pv = (colg <= rowg) ? EXP2F(s[t2][r] * c2) : 0.0f;
                    } else {
                        pv = EXP2F(s[t2][r] * c2);
                    }
                    lsum[r] += pv;
                    lds_p[wave][lq * 4 + r][t2 * 16 + l15] = f2bf(pv);
                }

            // ---- O += P @ V ----
#pragma unroll
            for (int kc = 0; kc < 2; ++kc) {
                short8 ap = *(const short8*)&lds_p[wave][l15][kc * 32 + lq * 8];
#pragma unroll
                for (int n = 0; n < 4; ++n) {
                    int off = (n * 16 + l15) * 128 + ((kc * 64 + lq * 16 + fsw) & 127);
                    short8 bv = *(const short8*)((const char*)vbuf + off);
                    o[n] = __builtin_amdgcn_mfma_f32_16x16x32_bf16(ap, bv, o[n], 0, 0, 0);
                }
            }
            __syncthreads();   // all waves done with kbuf/vbuf before next stage
        }

        // ---- row-sum reduce + epilogue: y = x + O/l ----
#pragma unroll
        for (int r = 0; r < 4; ++r) {
#pragma unroll
            for (int msk = 1; msk < 16; msk <<= 1) lsum[r] += __shfl_xor(lsum[r], msk, 64);
        }
        const float* xp = xf + (size_t)b * T * E + (size_t)h * 64;
        u16* yp = y + (size_t)b * T * E + (size_t)h * 64;
        float rl[4];
#pragma unroll
        for (int r = 0; r < 4; ++r) rl[r] = 1.0f / lsum[r];
#pragma unroll
        for (int n = 0; n < 4; ++n)
#pragma unroll
            for (int r = 0; r < 4; ++r) {
                int rowg = qt + lq * 4 + r;
                int col = n * 16 + l15;
                float val = o[n][r] * rl[r];
                float res = __builtin_nontemporal_load(xp + (size_t)rowg * E + col);
                yp[(size_t)rowg * E + col] = f2bf(res + val);
            }
    }
}

// ---------------------------------------------------------------------------
extern "C" void kernel_launch(void* const* d_in, const int* in_sizes, int n_in,
                              void* d_out, int out_size, void* d_ws, size_t ws_size,
                              hipStream_t stream) {
    const int B = 2, T = 2048, E = 1024;
    const int M = B * T;  // 4096

    const float* x  = (const float*)d_in[0];
    const float* Wq = (const float*)d_in[1];
    const float* Wk = (const float*)d_in[2];
    const float* Wv = (const float*)d_in[3];
    const float* Wf = (const float*)d_in[4];
    const float* bf = (const float*)d_in[5];
    float* out = (float*)d_out;

    u16* ws = (u16*)d_ws;
    const size_t WN = (size_t)E * E;      // 1M elems per weight
    const size_t XN = (size_t)M * E;      // 4M elems per activation
    u16* Wqkv  = ws;                       // [3E][E] fused transposed weights
    u16* WfT   = ws + 3 * WN;
    u16* xb    = ws + 4 * WN;              // dead after QKV GEMM -> vpack alias
    u16* qkv   = ws + 4 * WN + XN;         // [M][3E] = 3*XN elems
    u16* yb    = ws + 4 * WN + 4 * XN;
    u16* vpack = xb;                       // BH*T*64 = XN elems
    u16* kpk   = ws + 4 * WN + 5 * XN;     // optional dense K, XN elems
    const int packed = (ws_size >= (size_t)(4 * WN + 6 * XN) * sizeof(u16)) ? 1 : 0;

    conv_transpose_k<<<dim3(E / 32, E / 32, 4), dim3(32, 32), 0, stream>>>(
        Wq, Wk, Wv, Wf, Wqkv, Wqkv + WN, Wqkv + 2 * WN, WfT, E);
    conv_k<<<(int)(XN / 1024), 256, 0, stream>>>(x, xb, (int)XN);

    // fused QKV projection: [M,E] @ [E,3E] -> [M,3E]
    gemm_bt<<<dim3(M / 128, 3 * E / 128), 256, 0, stream>>>(xb, Wqkv, qkv, M, 3 * E, E);

    vpack_k<<<dim3(T / 32, 2, B * 16), dim3(32, 32), 0, stream>>>(qkv, vpack, T, E);
    if (packed)
        kpack_k<<<dim3(T / 32, B * 16), 256, 0, stream>>>(qkv, kpk, T, E);

    // grid (bh=32, qpair=16): head-per-XCD affinity, uniform 33 iters/block
    attn8_k<<<dim3(B * 16, T / 64 / 2), 256, 0, stream>>>(qkv, kpk, packed, vpack, x, yb, T, E);

    // FF: out = yb + relu(yb @ Wf + bf)
    gemm64_bt<<<dim3(M / 64, E / 128), 256, 0, stream>>>(yb, WfT, out, bf, yb, M, E, E);
}

// Round 12
// 204.850 us; speedup vs baseline: 2.0703x; 1.0735x over previous
//
#include <hip/hip_runtime.h>
#include <cstdint>
#include <cstddef>

typedef unsigned short u16;
typedef short short8 __attribute__((ext_vector_type(8)));
typedef float floatx4 __attribute__((ext_vector_type(4)));

__device__ __forceinline__ float bf2f(u16 u) {
    union { unsigned int i; float f; } v; v.i = ((unsigned int)u) << 16; return v.f;
}
__device__ __forceinline__ u16 f2bf(float f) {
    union { float f; unsigned int i; } v; v.f = f;
    unsigned int u = v.i;
    return (u16)((u + 0x7fffu + ((u >> 16) & 1u)) >> 16);
}

#if __has_builtin(__builtin_amdgcn_exp2f)
#define EXP2F(x) __builtin_amdgcn_exp2f(x)
#else
#define EXP2F(x) exp2f(x)
#endif

// async global->LDS, 16B per lane; LDS dest = wave-uniform base + lane*16
__device__ __forceinline__ void gload_lds16(const u16* g, void* lds_wave_base) {
    __builtin_amdgcn_global_load_lds(
        (__attribute__((address_space(1))) void*)g,
        (__attribute__((address_space(3))) void*)lds_wave_base,
        16, 0, 0);
}

// ---------------------------------------------------------------------------
// Convert+transpose 4 weight matrices (E x E, f32) -> bf16. Wt[n][k]=W[k][n].
// ---------------------------------------------------------------------------
__global__ void conv_transpose_k(const float* __restrict__ w0, const float* __restrict__ w1,
                                 const float* __restrict__ w2, const float* __restrict__ w3,
                                 u16* __restrict__ o0, u16* __restrict__ o1,
                                 u16* __restrict__ o2, u16* __restrict__ o3, int n) {
    __shared__ float t[32][33];
    const float* w; u16* o;
    switch (blockIdx.z) {
        case 0: w = w0; o = o0; break;
        case 1: w = w1; o = o1; break;
        case 2: w = w2; o = o2; break;
        default: w = w3; o = o3; break;
    }
    int tx = threadIdx.x, ty = threadIdx.y;
    int x0 = blockIdx.x * 32, y0 = blockIdx.y * 32;
    t[ty][tx] = w[(size_t)(y0 + ty) * n + x0 + tx];
    __syncthreads();
    o[(size_t)(x0 + ty) * n + y0 + tx] = f2bf(t[tx][ty]);
}

// ---------------------------------------------------------------------------
// Convert f32 -> bf16, vectorized.
// ---------------------------------------------------------------------------
__global__ void conv_k(const float* __restrict__ in, u16* __restrict__ out, int n) {
    int i = (blockIdx.x * blockDim.x + threadIdx.x) * 4;
    if (i >= n) return;
    float4 v = *(const float4*)&in[i];
    ushort4 o;
    o.x = f2bf(v.x); o.y = f2bf(v.y); o.z = f2bf(v.z); o.w = f2bf(v.w);
    *(ushort4*)&out[i] = o;
}

// ---------------------------------------------------------------------------
// V pack from per-head dense vbd[bh][t][64] -> per-64-chunk blocks
// vp[bh][kblk][d][tloc]. grid (T/32, 2, BH), block (32,32).
// ---------------------------------------------------------------------------
__global__ void vpack_k(const u16* __restrict__ vbd, u16* __restrict__ vp, int T) {
    __shared__ u16 t[32][33];
    int bh = blockIdx.z;
    int t0 = blockIdx.x * 32, d0 = blockIdx.y * 32;
    int tx = threadIdx.x, ty = threadIdx.y;
    t[ty][tx] = vbd[((size_t)bh * T + t0 + ty) * 64 + d0 + tx];
    __syncthreads();
    int kblk = t0 >> 6, tbase = t0 & 32;
    vp[(((size_t)bh * (T / 64) + kblk) * 64 + d0 + ty) * 64 + tbase + tx] = t[tx][ty];
}

// ---------------------------------------------------------------------------
// Fused QKV GEMM: [M,E] @ Wqkv[3E,E]^T, writing q/k/v directly in per-head
// dense layout [bh][t][64] (b = row>>11, t = row&2047, h = colE>>6, d=colE&63).
// 128x128 tile, BK=32, 4 waves x (4x4) MFMA, global_load_lds staging.
// Section (q/k/v) is uniform per block: bn/1024.
// ---------------------------------------------------------------------------
__global__ __launch_bounds__(256) void gemm_qkv(
    const u16* __restrict__ A, const u16* __restrict__ Bt,
    u16* __restrict__ qpk, u16* __restrict__ kpk, u16* __restrict__ vbd,
    int M, int T, int K) {
    __shared__ u16 lds_a[128][32];
    __shared__ u16 lds_b[128][32];

    const int tid = threadIdx.x;
    const int lane = tid & 63, wave = tid >> 6;
    const int wm = (wave >> 1) * 64, wn = (wave & 1) * 64;
    const int bm = blockIdx.x * 128, bn = blockIdx.y * 128;
    const int l15 = lane & 15, lq = lane >> 4;

    const int sec = bn >> 10;                 // 0=q,1=k,2=v (128 | 1024)
    u16* dst = (sec == 0) ? qpk : (sec == 1) ? kpk : vbd;
    const int bnE = bn & 1023;

    floatx4 acc[4][4];
#pragma unroll
    for (int i = 0; i < 4; ++i)
#pragma unroll
        for (int j = 0; j < 4; ++j) acc[i][j] = (floatx4)0.0f;

    for (int k0 = 0; k0 < K; k0 += 32) {
#pragma unroll
        for (int it = 0; it < 2; ++it) {
            int idx = it * 256 + tid;        // 0..511
            int row = idx >> 2;              // 0..127
            int c8 = (idx & 3) * 8;          // 0,8,16,24
            size_t ldsoff = (size_t)(it * 256 + wave * 64) * 16;  // bytes, wave-uniform
            gload_lds16(&A[(size_t)(bm + row) * K + k0 + c8], (char*)&lds_a[0][0] + ldsoff);
            gload_lds16(&Bt[(size_t)(bn + row) * K + k0 + c8], (char*)&lds_b[0][0] + ldsoff);
        }
        __syncthreads();

        short8 af[4], bfr[4];
#pragma unroll
        for (int i = 0; i < 4; ++i) af[i] = *(const short8*)&lds_a[wm + i * 16 + l15][lq * 8];
#pragma unroll
        for (int j = 0; j < 4; ++j) bfr[j] = *(const short8*)&lds_b[wn + j * 16 + l15][lq * 8];

#pragma unroll
        for (int i = 0; i < 4; ++i)
#pragma unroll
            for (int j = 0; j < 4; ++j)
                acc[i][j] = __builtin_amdgcn_mfma_f32_16x16x32_bf16(af[i], bfr[j], acc[i][j], 0, 0, 0);
        __syncthreads();
    }

#pragma unroll
    for (int i = 0; i < 4; ++i)
#pragma unroll
        for (int j = 0; j < 4; ++j)
#pragma unroll
            for (int r = 0; r < 4; ++r) {
                int row = bm + wm + i * 16 + lq * 4 + r;
                int colE = bnE + wn + j * 16 + l15;      // 0..1023
                int h = colE >> 6, d = colE & 63;
                int b = row >> 11, t = row & 2047;
                dst[(((size_t)(b * 16 + h) * T) + t) * 64 + d] = f2bf(acc[i][j][r]);
            }
}

// ---------------------------------------------------------------------------
// FF GEMM: 64x128 tile. Cf (f32) = bf2f(resid) + relu(acc + bias[col]).
// ---------------------------------------------------------------------------
__global__ __launch_bounds__(256) void gemm64_bt(
    const u16* __restrict__ A, const u16* __restrict__ Bt, float* __restrict__ Cf,
    const float* __restrict__ bias, const u16* __restrict__ resid,
    int M, int N, int K) {
    __shared__ u16 lds_a[64][32];
    __shared__ u16 lds_b[128][32];

    const int tid = threadIdx.x;
    const int lane = tid & 63, wave = tid >> 6;
    const int wm = (wave >> 1) * 32, wn = (wave & 1) * 64;
    const int bm = blockIdx.x * 64, bn = blockIdx.y * 128;
    const int l15 = lane & 15, lq = lane >> 4;

    floatx4 acc[2][4];
#pragma unroll
    for (int i = 0; i < 2; ++i)
#pragma unroll
        for (int j = 0; j < 4; ++j) acc[i][j] = (floatx4)0.0f;

    for (int k0 = 0; k0 < K; k0 += 32) {
        {
            int row = tid >> 2;              // 0..63
            int c8 = (tid & 3) * 8;
            size_t ldsoff = (size_t)(wave * 64) * 16;
            gload_lds16(&A[(size_t)(bm + row) * K + k0 + c8], (char*)&lds_a[0][0] + ldsoff);
        }
#pragma unroll
        for (int it = 0; it < 2; ++it) {
            int idx = it * 256 + tid;
            int row = idx >> 2;              // 0..127
            int c8 = (idx & 3) * 8;
            size_t ldsoff = (size_t)(it * 256 + wave * 64) * 16;
            gload_lds16(&Bt[(size_t)(bn + row) * K + k0 + c8], (char*)&lds_b[0][0] + ldsoff);
        }
        __syncthreads();

        short8 af[2], bfr[4];
#pragma unroll
        for (int i = 0; i < 2; ++i) af[i] = *(const short8*)&lds_a[wm + i * 16 + l15][lq * 8];
#pragma unroll
        for (int j = 0; j < 4; ++j) bfr[j] = *(const short8*)&lds_b[wn + j * 16 + l15][lq * 8];

#pragma unroll
        for (int i = 0; i < 2; ++i)
#pragma unroll
            for (int j = 0; j < 4; ++j)
                acc[i][j] = __builtin_amdgcn_mfma_f32_16x16x32_bf16(af[i], bfr[j], acc[i][j], 0, 0, 0);
        __syncthreads();
    }

#pragma unroll
    for (int i = 0; i < 2; ++i)
#pragma unroll
        for (int j = 0; j < 4; ++j)
#pragma unroll
            for (int r = 0; r < 4; ++r) {
                int row = bm + wm + i * 16 + lq * 4 + r;
                int col = bn + wn + j * 16 + l15;
                float v = acc[i][j][r];
                v = fmaxf(v + bias[col], 0.0f) + bf2f(resid[(size_t)row * N + col]);
                Cf[(size_t)row * N + col] = v;
            }
}

// ---------------------------------------------------------------------------
// Flash attention v9 = v8b + double-buffered K/V staging + 1 barrier/iter.
// Block = 4 waves = one 64-row Q block; causal pair {bx, 31-bx} -> uniform 33
// iterations. Per iteration: issue DMA for chunk kt+1 into the alternate LDS
// buffer, compute chunk kt, barrier (its vmcnt(0) drain waits on a DMA that
// had a full compute phase of slack -> staging latency off the chain).
// Q/K in per-head dense layout (stride 64); V pre-packed per 64-chunk.
// ---------------------------------------------------------------------------
#define STAGE(KT, BUF)                                                            \
    {                                                                             \
        const u16* kc_ = kb + (size_t)((KT) * 64 + r0) * 64 + swz0;               \
        gload_lds16(kc_, (char*)kbuf + (BUF) * 8192 + wave * 1024);               \
        gload_lds16(kc_ + 32 * 64, (char*)kbuf + (BUF) * 8192 + 4096 + wave * 1024); \
        const u16* vc_ = vp + (size_t)(KT) * 4096 + r0 * 64 + swz0;               \
        gload_lds16(vc_, (char*)vbuf + (BUF) * 8192 + wave * 1024);               \
        gload_lds16(vc_ + 32 * 64, (char*)vbuf + (BUF) * 8192 + 4096 + wave * 1024); \
    }

__global__ __launch_bounds__(256) void attn9_k(
    const u16* __restrict__ qpk, const u16* __restrict__ kpk,
    const u16* __restrict__ vpack, const float* __restrict__ xf,
    u16* __restrict__ y, int T, int E) {
    __shared__ u16 kbuf[2][64 * 64];        // double-buffered, cols XOR-swizzled
    __shared__ u16 vbuf[2][64 * 64];
    __shared__ u16 lds_p[4][16][72];        // wave-private P, 72-pad

    const int tid = threadIdx.x;
    const int lane = tid & 63, wave = tid >> 6;
    const int l15 = lane & 15, lq = lane >> 4;
    const int bh = blockIdx.x;              // grid.x = 32 -> head-per-XCD affinity
    const int b = bh >> 4, h = bh & 15;
    const int bx = blockIdx.y;              // 0..15 -> q-block pair {bx, 31-bx}

    const u16* qp = qpk + (size_t)bh * T * 64;
    const u16* kb = kpk + (size_t)bh * T * 64;
    const u16* vp = vpack + (size_t)bh * T * 64;    // [T/64][64][64] blocks

    const float c2 = 0.04508422f;  // log2(e)/32
    const int r0 = tid >> 3;            // staging row 0..31
    const int slot = tid & 7;           // staging 16B slot within row
    const int swz0 = ((slot - (r0 & 7)) & 7) * 8;   // source col elems (swizzle)
    const int fsw = (l15 & 7) * 16;     // fragment-read swizzle byte offset

#pragma unroll 1
    for (int p = 0; p < 2; ++p) {
        const int qb = p ? (31 - bx) : bx;          // q-block 0..31
        const int qt = qb * 64 + wave * 16;         // this wave's 16 rows
        const int nkb = qb + 1;

        short8 aq[2];
#pragma unroll
        for (int c = 0; c < 2; ++c)
            aq[c] = *(const short8*)&qp[(size_t)(qt + l15) * 64 + c * 32 + lq * 8];

        floatx4 o[4];
#pragma unroll
        for (int n = 0; n < 4; ++n) o[n] = (floatx4)0.0f;
        float lsum[4];
#pragma unroll
        for (int r = 0; r < 4; ++r) lsum[r] = 0.0f;

        // prologue: stage chunk 0 into buffer 0, drain
        STAGE(0, 0);
        __syncthreads();

#pragma unroll 1
        for (int kt = 0; kt < nkb; ++kt) {
            const int kc0 = kt * 64;
            const int cur = kt & 1;
            const int curoff = cur * 8192;   // byte offset into kbuf/vbuf

            // issue DMA for next chunk into the alternate buffer (no wait)
            if (kt + 1 < nkb) STAGE(kt + 1, cur ^ 1);

            // ---- S = Q K^T (16 rows x 64 cols) ----
            floatx4 s[4];
#pragma unroll
            for (int t2 = 0; t2 < 4; ++t2) {
                floatx4 sa = (floatx4)0.0f;
#pragma unroll
                for (int c = 0; c < 2; ++c) {
                    int off = (t2 * 16 + l15) * 128 + ((c * 64 + lq * 16 + fsw) & 127);
                    short8 bk = *(const short8*)((const char*)kbuf + curoff + off);
                    sa = __builtin_amdgcn_mfma_f32_16x16x32_bf16(aq[c], bk, sa, 0, 0, 0);
                }
                s[t2] = sa;
            }

            // ---- no-max softmax numerator, P -> wave-private LDS ----
            const bool partial = (kt == qb);   // block-uniform: only diagonal chunk
#pragma unroll
            for (int t2 = 0; t2 < 4; ++t2)
#pragma unroll
                for (int r = 0; r < 4; ++r) {
                    float pv;
                    if (partial) {
                        int colg = kc0 + t2 * 16 + l15;
                        int rowg = qt + lq * 4 + r;
                        pv = (colg <= rowg) ? EXP2F(s[t2][r] * c2) : 0.0f;
                    } else {
                        pv = EXP2F(s[t2][r] * c2);
                    }
                    lsum[r] += pv;
                    lds_p[wave][lq * 4 + r][t2 * 16 + l15] = f2bf(pv);
                }

            // ---- O += P @ V ----
#pragma unroll
            for (int kc = 0; kc < 2; ++kc) {
                short8 ap = *(const short8*)&lds_p[wave][l15][kc * 32 + lq * 8];
#pragma unroll
                for (int n = 0; n < 4; ++n) {
                    int off = (n * 16 + l15) * 128 + ((kc * 64 + lq * 16 + fsw) & 127);
                    short8 bv = *(const short8*)((const char*)vbuf + curoff + off);
                    o[n] = __builtin_amdgcn_mfma_f32_16x16x32_bf16(ap, bv, o[n], 0, 0, 0);
                }
            }
            // one barrier per iter: drains next-chunk DMA (full compute of
            // slack behind it) + orders buffer reuse across waves
            __syncthreads();
        }

        // ---- row-sum reduce + epilogue: y = x + O/l ----
#pragma unroll
        for (int r = 0; r < 4; ++r) {
#pragma unroll
            for (int msk = 1; msk < 16; msk <<= 1) lsum[r] += __shfl_xor(lsum[r], msk, 64);
        }
        const float* xp = xf + (size_t)b * T * E + (size_t)h * 64;
        u16* yp = y + (size_t)b * T * E + (size_t)h * 64;
        float rl[4];
#pragma unroll
        for (int r = 0; r < 4; ++r) rl[r] = 1.0f / lsum[r];
#pragma unroll
        for (int n = 0; n < 4; ++n)
#pragma unroll
            for (int r = 0; r < 4; ++r) {
                int rowg = qt + lq * 4 + r;
                int col = n * 16 + l15;
                float val = o[n][r] * rl[r];
                float res = __builtin_nontemporal_load(xp + (size_t)rowg * E + col);
                yp[(size_t)rowg * E + col] = f2bf(res + val);
            }
    }
}

// ---------------------------------------------------------------------------
extern "C" void kernel_launch(void* const* d_in, const int* in_sizes, int n_in,
                              void* d_out, int out_size, void* d_ws, size_t ws_size,
                              hipStream_t stream) {
    const int B = 2, T = 2048, E = 1024;
    const int M = B * T;  // 4096

    const float* x  = (const float*)d_in[0];
    const float* Wq = (const float*)d_in[1];
    const float* Wk = (const float*)d_in[2];
    const float* Wv = (const float*)d_in[3];
    const float* Wf = (const float*)d_in[4];
    const float* bf = (const float*)d_in[5];
    float* out = (float*)d_out;

    u16* ws = (u16*)d_ws;
    const size_t WN = (size_t)E * E;      // 1M elems per weight
    const size_t XN = (size_t)M * E;      // 4M elems per activation
    u16* Wqkv  = ws;                       // [3E][E] fused transposed weights
    u16* WfT   = ws + 3 * WN;
    u16* xb    = ws + 4 * WN;              // dead after QKV GEMM -> vpack alias
    u16* qpk   = ws + 4 * WN + XN;         // per-head dense q [bh][t][64]
    u16* kpk   = ws + 4 * WN + 2 * XN;     // per-head dense k
    u16* vbd   = ws + 4 * WN + 3 * XN;     // per-head dense v
    u16* yb    = ws + 4 * WN + 4 * XN;
    u16* vpack = xb;                       // [bh][T/64][64][64], aliases xb
    // total: 4*WN + 5*XN = 48 MB (same budget as the round-2 baseline)

    conv_transpose_k<<<dim3(E / 32, E / 32, 4), dim3(32, 32), 0, stream>>>(
        Wq, Wk, Wv, Wf, Wqkv, Wqkv + WN, Wqkv + 2 * WN, WfT, E);
    conv_k<<<(int)(XN / 1024), 256, 0, stream>>>(x, xb, (int)XN);

    // fused QKV projection, writing q/k/v per-head dense directly
    gemm_qkv<<<dim3(M / 128, 3 * E / 128), 256, 0, stream>>>(
        xb, Wqkv, qpk, kpk, vbd, M, T, E);

    vpack_k<<<dim3(T / 32, 2, B * 16), dim3(32, 32), 0, stream>>>(vbd, vpack, T);

    // grid (bh=32, qpair=16): head-per-XCD affinity, uniform 33 iters/block
    attn9_k<<<dim3(B * 16, T / 64 / 2), 256, 0, stream>>>(qpk, kpk, vpack, x, yb, T, E);

    // FF: out = yb + relu(yb @ Wf + bf)
    gemm64_bt<<<dim3(M / 64, E / 128), 256, 0, stream>>>(yb, WfT, out, bf, yb, M, E, E);
}